// Round 4
// baseline (2515.851 us; speedup 1.0000x reference)
//
#include <hip/hip_runtime.h>
#include <math.h>

#define N_NODES 100000
#define N_EDGES 1600000
#define HID     128
#define NGRAPH  256
#define SCHUNK  1024
#define NCHUNK  ((N_NODES + SCHUNK - 1) / SCHUNK)   // 98
#define GB      ((N_NODES + 63) / 64)               // 1563 gemm blocks per branch
#define GAT_NB  (N_NODES / 4)                       // 25000 gather blocks per branch
#define EB      ((N_EDGES + 255) / 256)             // 6250
#define NB      ((N_NODES + 255) / 256)             // 391
#define PB      ((N_NODES + 63) / 64)               // 1563 pool blocks per branch
#define NBUCK   ((N_NODES + 511) / 512)             // 196 buckets (512 nodes each)

typedef unsigned short u16;
typedef unsigned int   u32;
typedef __attribute__((ext_vector_type(8))) short    bf16x8;
typedef __attribute__((ext_vector_type(4))) float    f32x4;
typedef __attribute__((ext_vector_type(8))) unsigned short u16x8;

__device__ inline float b2f(u16 u) {
    union { unsigned int i; float f; } x; x.i = ((unsigned int)u) << 16; return x.f;
}
__device__ inline u16 f2b(float f) {
    union { float f; unsigned int i; } x; x.f = f;
    unsigned int r = x.i + 0x7fff + ((x.i >> 16) & 1);   // round-to-nearest-even
    return (u16)(r >> 16);
}

// ============================= setup kernels =============================

__global__ void count2_kernel(const int* __restrict__ sc_ei, const int* __restrict__ fc_ei,
                              int* __restrict__ c_sc, int* __restrict__ c_fc) {
    int b = blockIdx.x;
    const int* ei = (b >= EB) ? fc_ei : sc_ei;
    int* counts   = (b >= EB) ? c_fc  : c_sc;
    int e = (b >= EB ? b - EB : b) * 256 + threadIdx.x;
    if (e < N_EDGES) atomicAdd(&counts[ei[N_EDGES + e]], 1);
}

__global__ void dis2_kernel(const int* __restrict__ c_sc, const int* __restrict__ c_fc,
                            float* __restrict__ d_sc, float* __restrict__ d_fc) {
    int b = blockIdx.x;
    const int* counts = (b >= NB) ? c_fc : c_sc;
    float* dis        = (b >= NB) ? d_fc : d_sc;
    int i = (b >= NB ? b - NB : b) * 256 + threadIdx.x;
    if (i < N_NODES) dis[i] = rsqrtf((float)counts[i] + 1.0f);
}

// ---- 3-phase multi-block exclusive scan (both branches in one grid) ----
__global__ __launch_bounds__(256) void block_sum_kernel(const int* __restrict__ c_sc,
                                                        const int* __restrict__ c_fc,
                                                        int* __restrict__ bsum) {
    int branch = blockIdx.x / NCHUNK;
    int chunk  = blockIdx.x % NCHUNK;
    const int* counts = branch ? c_fc : c_sc;
    int base = chunk * SCHUNK;
    int tid = threadIdx.x;
    int v = 0;
    for (int i = tid; i < SCHUNK; i += 256) {
        int idx = base + i;
        if (idx < N_NODES) v += counts[idx];
    }
    __shared__ int red[4];
#pragma unroll
    for (int off = 32; off; off >>= 1) v += __shfl_down(v, off);
    if ((tid & 63) == 0) red[tid >> 6] = v;
    __syncthreads();
    if (tid == 0) bsum[blockIdx.x] = red[0] + red[1] + red[2] + red[3];
}

__global__ __launch_bounds__(256) void scan_tops_kernel(int* __restrict__ bsum) {
    __shared__ int lds[2][128];
    int tid = threadIdx.x;
    int branch = tid >> 7;
    int i = tid & 127;
    int orig = (i < NCHUNK) ? bsum[branch * NCHUNK + i] : 0;
    lds[branch][i] = orig;
    __syncthreads();
    for (int off = 1; off < 128; off <<= 1) {
        int t = (i >= off) ? lds[branch][i - off] : 0;
        __syncthreads();
        lds[branch][i] += t;
        __syncthreads();
    }
    if (i < NCHUNK) bsum[branch * NCHUNK + i] = lds[branch][i] - orig;  // exclusive
}

__global__ __launch_bounds__(256) void scan_final_kernel(
        const int* __restrict__ c_sc, const int* __restrict__ c_fc,
        const int* __restrict__ bsum,
        int* __restrict__ off_sc, int* __restrict__ off_fc) {
    int branch = blockIdx.x / NCHUNK;
    int chunk  = blockIdx.x % NCHUNK;
    const int* counts = branch ? c_fc : c_sc;
    int* offs = branch ? off_fc : off_sc;
    int tid = threadIdx.x;
    int base = chunk * SCHUNK + tid * 4;
    int v[4], s = 0;
#pragma unroll
    for (int k = 0; k < 4; ++k) {
        int idx = base + k;
        v[k] = (idx < N_NODES) ? counts[idx] : 0;
        s += v[k];
    }
    __shared__ int lds[256];
    lds[tid] = s;
    __syncthreads();
    for (int off = 1; off < 256; off <<= 1) {
        int t = (tid >= off) ? lds[tid - off] : 0;
        __syncthreads();
        lds[tid] += t;
        __syncthreads();
    }
    int prefix = bsum[blockIdx.x] + lds[tid] - s;
#pragma unroll
    for (int k = 0; k < 4; ++k) {
        int idx = base + k;
        if (idx < N_NODES) offs[idx] = prefix;
        prefix += v[k];
    }
    if (blockIdx.x == 0 && tid == 0) { off_sc[N_NODES] = N_EDGES; off_fc[N_NODES] = N_EDGES; }
}

// ---- bucket cursor init: bcur[branch][k] = off[k*512] ----
__global__ void bcur_init_kernel(const int* __restrict__ off_sc, const int* __restrict__ off_fc,
                                 int* __restrict__ bcur) {
    int t = threadIdx.x;  // one block of 512 covers 2*NBUCK=392
    if (t >= 2 * NBUCK) return;
    int branch = t >= NBUCK;
    int k = branch ? t - NBUCK : t;
    const int* off = branch ? off_fc : off_sc;
    bcur[t] = off[k << 9];
}

// ---- pass A: bucket-scatter packed records (src<<9 | dst&511) ----
__global__ void buildA_kernel(const int* __restrict__ sc_ei, const int* __restrict__ fc_ei,
                              int* __restrict__ bcur,
                              u32* __restrict__ tmp_sc, u32* __restrict__ tmp_fc) {
    int b = blockIdx.x;
    int branch = b >= EB;
    const int* ei = branch ? fc_ei : sc_ei;
    u32* tmp      = branch ? tmp_fc : tmp_sc;
    int* bc       = bcur + (branch ? NBUCK : 0);
    int e = (branch ? b - EB : b) * 256 + threadIdx.x;
    if (e >= N_EDGES) return;
    int s = ei[e], d = ei[N_EDGES + e];
    int bucket = d >> 9;
    int pos = atomicAdd(&bc[bucket], 1);
    tmp[pos] = ((u32)s << 9) | (u32)(d & 511);
}

// ---- pass B: per-bucket LDS-cursor scatter into final CSR srcs ----
__global__ __launch_bounds__(256) void buildB_kernel(
        const u32* __restrict__ tmp_sc, const u32* __restrict__ tmp_fc,
        const int* __restrict__ off_sc, const int* __restrict__ off_fc,
        int* __restrict__ srcs_sc, int* __restrict__ srcs_fc) {
    int b = blockIdx.x;
    int branch = b >= NBUCK;
    int bucket = branch ? b - NBUCK : b;
    const u32* tmp = branch ? tmp_fc : tmp_sc;
    const int* off = branch ? off_fc : off_sc;
    int* srcs      = branch ? srcs_fc : srcs_sc;
    int node0 = bucket << 9;
    int nEnd = min(node0 + 512, N_NODES);
    __shared__ int cur[512];
    int tid = threadIdx.x;
    for (int i = tid; i < 512; i += 256)
        cur[i] = (node0 + i <= N_NODES) ? off[node0 + i] : N_EDGES;
    __syncthreads();
    int beg = off[node0];
    int end = off[nEnd];
    for (int r = beg + tid; r < end; r += 256) {
        u32 rec = tmp[r];
        int local = rec & 511;
        int src = rec >> 9;
        int pos = atomicAdd(&cur[local], 1);
        srcs[pos] = src;
    }
}

// ---- pre-convert+transpose weights: Wt[l'][n][k] = W[l][k][n] (bf16), l' = branch*3+l ----
__global__ void convert_w_kernel(const float* __restrict__ sc_W, const float* __restrict__ fc_W,
                                 u16* __restrict__ Wt) {
    int idx = blockIdx.x * 256 + threadIdx.x;  // 6*16384 total
    if (idx >= 6 * 16384) return;
    int lp = idx >> 14;
    int r = idx & 16383;
    int n = r >> 7, k = r & 127;
    const float* W = (lp >= 3) ? fc_W : sc_W;
    int l = (lp >= 3) ? lp - 3 : lp;
    Wt[idx] = f2b(W[(size_t)l * 16384 + k * 128 + n]);
}

// ============================= MFMA GEMM: H'[n] = (bf16(A[n]) @ W) * dis[n] =============================
// block = 256 threads (4 waves); tile 64 rows x 128 cols; whole W in LDS.
// a_fp32: layer-0 reads fp32 inputs; later layers read bf16 x. dis folded into epilogue.
__global__ __launch_bounds__(256) void gemm2_kernel(
        const void* __restrict__ A_sc, const void* __restrict__ A_fc, int a_fp32,
        const u16* __restrict__ Wt, int layer,
        const float* __restrict__ d_sc, const float* __restrict__ d_fc,
        u16* __restrict__ H_sc, u16* __restrict__ H_fc) {
    int branch = blockIdx.x >= GB;
    int blk = branch ? blockIdx.x - GB : blockIdx.x;
    const void* A = branch ? A_fc : A_sc;
    const float* dis = branch ? d_fc : d_sc;
    u16* H = branch ? H_fc : H_sc;
    const u16* W = Wt + (((size_t)branch * 3 + layer) << 14);

    __shared__ u16 Alds[64 * 136];   // rows padded to 136 u16 (272 B)
    __shared__ u16 Wlds[128 * 136];  // Wt rows: n-major, k contiguous
    const int tid = threadIdx.x;
    const int row0 = blk * 64;

    if (a_fp32) {
        const float* Af = (const float*)A;
#pragma unroll
        for (int i = 0; i < 8; ++i) {
            int idx = tid + i * 256;
            int r = idx >> 5, f = idx & 31;
            int grow = row0 + r;
            float4 v = (grow < N_NODES) ? *(const float4*)&Af[(size_t)grow * 128 + f * 4]
                                        : make_float4(0.f, 0.f, 0.f, 0.f);
            ushort4 o;
            o.x = f2b(v.x); o.y = f2b(v.y); o.z = f2b(v.z); o.w = f2b(v.w);
            *(ushort4*)&Alds[r * 136 + f * 4] = o;
        }
    } else {
        const u16* Ab = (const u16*)A;
#pragma unroll
        for (int i = 0; i < 4; ++i) {
            int idx = tid + i * 256;
            int r = idx >> 4, f = idx & 15;
            int grow = row0 + r;
            u16x8 v = {};
            if (grow < N_NODES) v = *(const u16x8*)&Ab[(size_t)grow * 128 + f * 8];
            *(u16x8*)&Alds[r * 136 + f * 8] = v;
        }
    }
#pragma unroll
    for (int i = 0; i < 8; ++i) {
        int idx = tid + i * 256;
        int n = idx >> 4, f = idx & 15;
        *(u16x8*)&Wlds[n * 136 + f * 8] = *(const u16x8*)&W[n * 128 + f * 8];
    }
    __syncthreads();

    const int wv = tid >> 6;
    const int lane = tid & 63;
    const int m = lane & 15;       // row (A) / col (B) within 16-tile
    const int quad = lane >> 4;    // k-subchunk

    bf16x8 af[4];
#pragma unroll
    for (int kt = 0; kt < 4; ++kt)
        af[kt] = *(const bf16x8*)&Alds[(wv * 16 + m) * 136 + kt * 32 + quad * 8];

    f32x4 acc[8];
#pragma unroll
    for (int ct = 0; ct < 8; ++ct) { acc[ct][0] = 0.f; acc[ct][1] = 0.f; acc[ct][2] = 0.f; acc[ct][3] = 0.f; }

#pragma unroll
    for (int ct = 0; ct < 8; ++ct) {
#pragma unroll
        for (int kt = 0; kt < 4; ++kt) {
            bf16x8 bf = *(const bf16x8*)&Wlds[(ct * 16 + m) * 136 + kt * 32 + quad * 8];
            acc[ct] = __builtin_amdgcn_mfma_f32_16x16x32_bf16(af[kt], bf, acc[ct], 0, 0, 0);
        }
    }

    // fold dis: rows quad*4..quad*4+3 of this wave's 16-row tile (contiguous -> float4)
    float4 dv = *(const float4*)&dis[row0 + wv * 16 + quad * 4];  // ws-padded, OOB-safe
#pragma unroll
    for (int ct = 0; ct < 8; ++ct) {
        acc[ct][0] *= dv.x; acc[ct][1] *= dv.y; acc[ct][2] *= dv.z; acc[ct][3] *= dv.w;
    }

    // epilogue: C/D layout col=lane&15, row=quad*4+reg -> LDS -> coalesced bf16 stores
#pragma unroll
    for (int ct = 0; ct < 8; ++ct)
#pragma unroll
        for (int r = 0; r < 4; ++r)
            Alds[(wv * 16 + quad * 4 + r) * 136 + ct * 16 + m] = f2b(acc[ct][r]);
    __syncthreads();
#pragma unroll
    for (int i = 0; i < 4; ++i) {
        int idx = i * 64 + lane;
        int r = idx >> 4, f = idx & 15;
        int grow = row0 + wv * 16 + r;
        if (grow < N_NODES)
            *(u16x8*)&H[(size_t)grow * 128 + f * 8] = *(const u16x8*)&Alds[(wv * 16 + r) * 136 + f * 8];
    }
}

// ============================= GCN aggregation: x[n] = relu(dis[n]*(sum h'[src] + h'[n]) + b) =============================
__global__ __launch_bounds__(256) void gather2_kernel(
        const u16* __restrict__ h_sc, const u16* __restrict__ h_fc,
        const int* __restrict__ srcs_sc, const int* __restrict__ srcs_fc,
        const int* __restrict__ off_sc, const int* __restrict__ off_fc,
        const float* __restrict__ d_sc, const float* __restrict__ d_fc,
        const float* __restrict__ b_sc, const float* __restrict__ b_fc,
        u16* __restrict__ x_sc, u16* __restrict__ x_fc) {
    int bb = blockIdx.x;
    int branch = bb >= GAT_NB;
    if (branch) bb -= GAT_NB;
    const u16* h    = branch ? h_fc : h_sc;
    const int* srcs = branch ? srcs_fc : srcs_sc;
    const int* offs = branch ? off_fc : off_sc;
    const float* dis = branch ? d_fc : d_sc;
    const float* bias = branch ? b_fc : b_sc;
    u16* xout = branch ? x_fc : x_sc;

    int node = bb * 4 + (threadIdx.x >> 6);
    int lane = threadIdx.x & 63;
    int half = lane >> 5;           // which edge of a pair this half-wave owns
    int c = (lane & 31) * 4;        // feature chunk
    int beg = offs[node], end = offs[node + 1];
    float ax = 0.f, ay = 0.f, az = 0.f, aw = 0.f;
    int j = beg + half;
    // two edges in flight per half-wave => 4 per wave
    for (; j + 2 < end; j += 4) {
        int s0 = srcs[j], s1 = srcs[j + 2];
        ushort4 v0 = *(const ushort4*)&h[(size_t)s0 * 128 + c];
        ushort4 v1 = *(const ushort4*)&h[(size_t)s1 * 128 + c];
        ax += b2f(v0.x) + b2f(v1.x);
        ay += b2f(v0.y) + b2f(v1.y);
        az += b2f(v0.z) + b2f(v1.z);
        aw += b2f(v0.w) + b2f(v1.w);
    }
    if (j < end) {
        int s0 = srcs[j];
        ushort4 v0 = *(const ushort4*)&h[(size_t)s0 * 128 + c];
        ax += b2f(v0.x);
        ay += b2f(v0.y);
        az += b2f(v0.z);
        aw += b2f(v0.w);
    }
    ax += __shfl_xor(ax, 32);
    ay += __shfl_xor(ay, 32);
    az += __shfl_xor(az, 32);
    aw += __shfl_xor(aw, 32);
    if (half == 0) {
        float dn = dis[node];
        ushort4 hv = *(const ushort4*)&h[(size_t)node * 128 + c];  // h' self row
        float4 b4 = *(const float4*)&bias[c];
        ushort4 o;
        o.x = f2b(fmaxf(dn * (ax + b2f(hv.x)) + b4.x, 0.f));
        o.y = f2b(fmaxf(dn * (ay + b2f(hv.y)) + b4.y, 0.f));
        o.z = f2b(fmaxf(dn * (az + b2f(hv.z)) + b4.z, 0.f));
        o.w = f2b(fmaxf(dn * (aw + b2f(hv.w)) + b4.w, 0.f));
        *(ushort4*)&xout[(size_t)node * 128 + c] = o;
    }
}

// ============================= pooling (batch is sorted; x is bf16, fp32 accumulate) =============================
__global__ __launch_bounds__(128) void pool2_kernel(const u16* __restrict__ x_sc,
                                                    const u16* __restrict__ x_fc,
                                                    const int* __restrict__ batch,
                                                    float* __restrict__ g_sc,
                                                    float* __restrict__ g_fc) {
    int b = blockIdx.x;
    const u16* x = (b >= PB) ? x_fc : x_sc;
    float* g     = (b >= PB) ? g_fc : g_sc;
    int blk = (b >= PB) ? b - PB : b;
    int c = threadIdx.x;
    int start = blk * 64;
    if (start >= N_NODES) return;
    int endn = min(start + 64, N_NODES);
    float acc = 0.f;
    int cur = batch[start];
    for (int i = start; i < endn; ++i) {
        int bb = batch[i];
        if (bb != cur) {
            atomicAdd(&g[(size_t)cur * 128 + c], acc);
            acc = 0.f;
            cur = bb;
        }
        acc += b2f(x[(size_t)i * 128 + c]);
    }
    atomicAdd(&g[(size_t)cur * 128 + c], acc);
}

// ============================= row L2-normalize =============================
__global__ __launch_bounds__(64) void normalize_kernel(const float* __restrict__ g_sc,
                                                       const float* __restrict__ g_fc,
                                                       float* __restrict__ n_sc,
                                                       float* __restrict__ n_fc) {
    int r = blockIdx.x & 255;
    const float* g = (blockIdx.x < 256) ? g_sc : g_fc;
    float* o = (blockIdx.x < 256) ? n_sc : n_fc;
    int c = threadIdx.x;
    float v0 = g[r * 128 + c], v1 = g[r * 128 + c + 64];
    float ss = v0 * v0 + v1 * v1;
#pragma unroll
    for (int off = 32; off; off >>= 1) ss += __shfl_xor(ss, off);
    float inv = 1.0f / fmaxf(sqrtf(ss), 1e-12f);
    o[r * 128 + c] = v0 * inv;
    o[r * 128 + c + 64] = v1 * inv;
}

// ============================= classifier head =============================
__global__ __launch_bounds__(128) void head_kernel(const float* __restrict__ g_sc,
                                                   const float* __restrict__ g_fc,
                                                   const float* __restrict__ W1,
                                                   const float* __restrict__ b1,
                                                   const float* __restrict__ W2,
                                                   const float* __restrict__ b2,
                                                   float* __restrict__ out) {
    __shared__ float cat[256];
    __shared__ float red[4];
    int i = blockIdx.x, c = threadIdx.x;
    cat[c] = g_sc[i * 128 + c];
    cat[128 + c] = g_fc[i * 128 + c];
    __syncthreads();
    float acc = b1[c];
    for (int k = 0; k < 256; ++k) acc += cat[k] * W1[k * 128 + c];
    float z = fmaxf(acc, 0.f);
    float l0 = z * W2[c * 2 + 0];
    float l1 = z * W2[c * 2 + 1];
#pragma unroll
    for (int off = 32; off; off >>= 1) {
        l0 += __shfl_xor(l0, off);
        l1 += __shfl_xor(l1, off);
    }
    if ((c & 63) == 0) {
        red[(c >> 6) * 2 + 0] = l0;
        red[(c >> 6) * 2 + 1] = l1;
    }
    __syncthreads();
    if (c == 0) {
        float L0 = red[0] + red[2] + b2[0];
        float L1 = red[1] + red[3] + b2[1];
        float m = fmaxf(L0, L1);
        float lse = m + logf(expf(L0 - m) + expf(L1 - m));
        out[i * 2 + 0] = L0 - lse;
        out[i * 2 + 1] = L1 - lse;
    }
}

// ============================= contrastive loss =============================
__global__ __launch_bounds__(256) void contrast_kernel(const float* __restrict__ n_sc,
                                                       const float* __restrict__ n_fc,
                                                       float* __restrict__ loss_acc) {
    __shared__ float arow[128];
    __shared__ float redm[4];
    __shared__ float reds[4];
    __shared__ float diag_s;
    int b = blockIdx.x;
    int i = b & 255;
    bool which = b >= 256;
    const float* A  = which ? n_fc : n_sc;
    const float* B1 = which ? n_sc : n_fc;
    const float* B2 = which ? n_fc : n_sc;
    int j = threadIdx.x;
    if (j < 128) arow[j] = A[i * 128 + j];
    __syncthreads();
    float d1 = 0.f, d2 = 0.f;
    for (int k = 0; k < 128; ++k) {
        float a = arow[k];
        d1 += a * B1[(size_t)j * 128 + k];
        d2 += a * B2[(size_t)j * 128 + k];
    }
    const float t = 2.0f;  // 1/TEMPERATURE
    float v1 = t * d1;
    float v2 = (j == i) ? 0.0f : 0.8f * t * d2;
    if (j == i) diag_s = v1;
    float m = fmaxf(v1, v2);
#pragma unroll
    for (int off = 32; off; off >>= 1) m = fmaxf(m, __shfl_xor(m, off));
    if ((j & 63) == 0) redm[j >> 6] = m;
    __syncthreads();
    m = fmaxf(fmaxf(redm[0], redm[1]), fmaxf(redm[2], redm[3]));
    float s = expf(v1 - m) + expf(v2 - m);
#pragma unroll
    for (int off = 32; off; off >>= 1) s += __shfl_xor(s, off);
    if ((j & 63) == 0) reds[j >> 6] = s;
    __syncthreads();
    if (j == 0) {
        float S = reds[0] + reds[1] + reds[2] + reds[3];
        float lse = m + logf(S);
        atomicAdd(loss_acc, lse - diag_s);
    }
}

__global__ void final_add(float* __restrict__ out, const float* __restrict__ loss) {
    int t = threadIdx.x;
    if (t < 512) out[t] += loss[0] * (1.0f / 512.0f);
}

// ============================= launch =============================

extern "C" void kernel_launch(void* const* d_in, const int* in_sizes, int n_in,
                              void* d_out, int out_size, void* d_ws, size_t ws_size,
                              hipStream_t stream) {
    const float* sc_x  = (const float*)d_in[0];
    const float* fc_x  = (const float*)d_in[1];
    const int*   sc_ei = (const int*)d_in[2];
    const int*   fc_ei = (const int*)d_in[3];
    const int*   batch = (const int*)d_in[4];
    const float* sc_W  = (const float*)d_in[5];
    const float* sc_b  = (const float*)d_in[6];
    const float* fc_W  = (const float*)d_in[7];
    const float* fc_b  = (const float*)d_in[8];
    const float* fc1_W = (const float*)d_in[9];
    const float* fc1_b = (const float*)d_in[10];
    const float* fc2_W = (const float*)d_in[11];
    const float* fc2_b = (const float*)d_in[12];
    float* out = (float*)d_out;

    const size_t NF = (size_t)N_NODES * HID;  // 12.8M elements

    float* ws = (float*)d_ws;
    float* dis_sc = ws;                // N f32 (gemm epilogue reads float4 past end -> padded by dis_fc)
    float* dis_fc = dis_sc + N_NODES;  // N f32 (padded by g arrays after)
    float* g_sc  = dis_fc + N_NODES;   // g_sc,g_fc contiguous for one memset
    float* g_fc  = g_sc + NGRAPH * HID;
    float* n_sc  = g_fc + NGRAPH * HID;
    float* n_fc  = n_sc + NGRAPH * HID;
    float* lossp = n_fc + NGRAPH * HID;  // 1 (+pad)
    u16* h_sc    = (u16*)(lossp + 4);    // NF bf16 (h' = h*dis)
    u16* h_fc    = h_sc + NF;
    u16* x_sc    = h_fc + NF;            // NF bf16 activations
    u16* x_fc    = x_sc + NF;
    u16* Wtb     = x_fc + NF;            // 6*16384 bf16 (transposed weights)
    int* srcs_sc   = (int*)(Wtb + 6 * 16384);  // E
    int* srcs_fc   = srcs_sc + N_EDGES;
    u32* tmp_sc    = (u32*)(srcs_fc + N_EDGES);  // E packed records
    u32* tmp_fc    = tmp_sc + N_EDGES;
    int* counts_sc = (int*)(tmp_fc + N_EDGES);   // N (contiguous pair for memset)
    int* counts_fc = counts_sc + N_NODES;
    int* off_sc    = counts_fc + N_NODES;  // N+1
    int* off_fc    = off_sc + (N_NODES + 1);
    int* bcur      = off_fc + (N_NODES + 1);  // 2*NBUCK
    int* bsum      = bcur + 2 * NBUCK;        // 2*NCHUNK
    (void)ws_size; (void)n_in; (void)in_sizes; (void)out_size;

    // ---- CSR build (bucketed two-pass, both branches per dispatch) ----
    hipMemsetAsync(counts_sc, 0, 2 * N_NODES * sizeof(int), stream);
    count2_kernel<<<2 * EB, 256, 0, stream>>>(sc_ei, fc_ei, counts_sc, counts_fc);
    dis2_kernel<<<2 * NB, 256, 0, stream>>>(counts_sc, counts_fc, dis_sc, dis_fc);
    block_sum_kernel<<<2 * NCHUNK, 256, 0, stream>>>(counts_sc, counts_fc, bsum);
    scan_tops_kernel<<<1, 256, 0, stream>>>(bsum);
    scan_final_kernel<<<2 * NCHUNK, 256, 0, stream>>>(counts_sc, counts_fc, bsum, off_sc, off_fc);
    bcur_init_kernel<<<1, 512, 0, stream>>>(off_sc, off_fc, bcur);
    buildA_kernel<<<2 * EB, 256, 0, stream>>>(sc_ei, fc_ei, bcur, tmp_sc, tmp_fc);
    buildB_kernel<<<2 * NBUCK, 256, 0, stream>>>(tmp_sc, tmp_fc, off_sc, off_fc, srcs_sc, srcs_fc);
    convert_w_kernel<<<(6 * 16384 + 255) / 256, 256, 0, stream>>>(sc_W, fc_W, Wtb);

    // ---- 3 GCN layers, both branches per launch ----
    for (int l = 0; l < 3; ++l) {
        const void* a_sc = (l == 0) ? (const void*)sc_x : (const void*)x_sc;
        const void* a_fc = (l == 0) ? (const void*)fc_x : (const void*)x_fc;
        gemm2_kernel<<<2 * GB, 256, 0, stream>>>(a_sc, a_fc, (l == 0) ? 1 : 0, Wtb, l,
                                                 dis_sc, dis_fc, h_sc, h_fc);
        gather2_kernel<<<2 * GAT_NB, 256, 0, stream>>>(
            h_sc, h_fc, srcs_sc, srcs_fc, off_sc, off_fc,
            dis_sc, dis_fc, sc_b + (size_t)l * HID, fc_b + (size_t)l * HID, x_sc, x_fc);
    }

    // ---- pooling ----
    hipMemsetAsync(g_sc, 0, 2 * NGRAPH * HID * sizeof(float), stream);
    pool2_kernel<<<2 * PB, 128, 0, stream>>>(x_sc, x_fc, batch, g_sc, g_fc);

    // ---- head + contrastive ----
    normalize_kernel<<<512, 64, 0, stream>>>(g_sc, g_fc, n_sc, n_fc);
    head_kernel<<<NGRAPH, 128, 0, stream>>>(g_sc, g_fc, fc1_W, fc1_b, fc2_W, fc2_b, out);
    hipMemsetAsync(lossp, 0, sizeof(float), stream);
    contrast_kernel<<<512, 256, 0, stream>>>(n_sc, n_fc, lossp);
    final_add<<<1, 512, 0, stream>>>(out, lossp);
}

// Round 7
// 1148.367 us; speedup vs baseline: 2.1908x; 2.1908x over previous
//
#include <hip/hip_runtime.h>
#include <math.h>

#define N_NODES 100000
#define N_EDGES 1600000
#define HID     128
#define NGRAPH  256
#define SCHUNK  1024
#define NCHUNK  ((N_NODES + SCHUNK - 1) / SCHUNK)   // 98
#define GB      ((N_NODES + 63) / 64)               // 1563 gemm blocks per branch
#define GAT_NB  (N_NODES / 4)                       // 25000 gather blocks per branch
#define EB      ((N_EDGES + 255) / 256)             // 6250
#define NB      ((N_NODES + 255) / 256)             // 391
#define PB      ((N_NODES + 63) / 64)               // 1563 pool blocks per branch

typedef unsigned short u16;
typedef unsigned int   u32;
typedef __attribute__((ext_vector_type(8))) short    bf16x8;
typedef __attribute__((ext_vector_type(4))) float    f32x4;
typedef __attribute__((ext_vector_type(8))) unsigned short u16x8;

__device__ inline float b2f(u16 u) {
    union { unsigned int i; float f; } x; x.i = ((unsigned int)u) << 16; return x.f;
}
__device__ inline u16 f2b(float f) {
    union { float f; unsigned int i; } x; x.f = f;
    unsigned int r = x.i + 0x7fff + ((x.i >> 16) & 1);   // round-to-nearest-even
    return (u16)(r >> 16);
}

// ============================= setup kernels =============================

__global__ void count2_kernel(const int* __restrict__ sc_ei, const int* __restrict__ fc_ei,
                              int* __restrict__ c_sc, int* __restrict__ c_fc) {
    int b = blockIdx.x;
    const int* ei = (b >= EB) ? fc_ei : sc_ei;
    int* counts   = (b >= EB) ? c_fc  : c_sc;
    int e = (b >= EB ? b - EB : b) * 256 + threadIdx.x;
    if (e < N_EDGES) atomicAdd(&counts[ei[N_EDGES + e]], 1);
}

__global__ void dis2_kernel(const int* __restrict__ c_sc, const int* __restrict__ c_fc,
                            float* __restrict__ d_sc, float* __restrict__ d_fc) {
    int b = blockIdx.x;
    const int* counts = (b >= NB) ? c_fc : c_sc;
    float* dis        = (b >= NB) ? d_fc : d_sc;
    int i = (b >= NB ? b - NB : b) * 256 + threadIdx.x;
    if (i < N_NODES) dis[i] = rsqrtf((float)counts[i] + 1.0f);
}

// ---- 3-phase multi-block exclusive scan (both branches in one grid) ----
__global__ __launch_bounds__(256) void block_sum_kernel(const int* __restrict__ c_sc,
                                                        const int* __restrict__ c_fc,
                                                        int* __restrict__ bsum) {
    int branch = blockIdx.x / NCHUNK;
    int chunk  = blockIdx.x % NCHUNK;
    const int* counts = branch ? c_fc : c_sc;
    int base = chunk * SCHUNK;
    int tid = threadIdx.x;
    int v = 0;
    for (int i = tid; i < SCHUNK; i += 256) {
        int idx = base + i;
        if (idx < N_NODES) v += counts[idx];
    }
    __shared__ int red[4];
#pragma unroll
    for (int off = 32; off; off >>= 1) v += __shfl_down(v, off);
    if ((tid & 63) == 0) red[tid >> 6] = v;
    __syncthreads();
    if (tid == 0) bsum[blockIdx.x] = red[0] + red[1] + red[2] + red[3];
}

__global__ __launch_bounds__(256) void scan_tops_kernel(int* __restrict__ bsum) {
    __shared__ int lds[2][128];
    int tid = threadIdx.x;
    int branch = tid >> 7;
    int i = tid & 127;
    int orig = (i < NCHUNK) ? bsum[branch * NCHUNK + i] : 0;
    lds[branch][i] = orig;
    __syncthreads();
    for (int off = 1; off < 128; off <<= 1) {
        int t = (i >= off) ? lds[branch][i - off] : 0;
        __syncthreads();
        lds[branch][i] += t;
        __syncthreads();
    }
    if (i < NCHUNK) bsum[branch * NCHUNK + i] = lds[branch][i] - orig;  // exclusive
}

__global__ __launch_bounds__(256) void scan_final_kernel(
        const int* __restrict__ c_sc, const int* __restrict__ c_fc,
        const int* __restrict__ bsum,
        int* __restrict__ off_sc, int* __restrict__ off_fc,
        int* __restrict__ cur_sc, int* __restrict__ cur_fc) {
    int branch = blockIdx.x / NCHUNK;
    int chunk  = blockIdx.x % NCHUNK;
    const int* counts = branch ? c_fc : c_sc;
    int* offs = branch ? off_fc : off_sc;
    int* cur  = branch ? cur_fc : cur_sc;
    int tid = threadIdx.x;
    int base = chunk * SCHUNK + tid * 4;
    int v[4], s = 0;
#pragma unroll
    for (int k = 0; k < 4; ++k) {
        int idx = base + k;
        v[k] = (idx < N_NODES) ? counts[idx] : 0;
        s += v[k];
    }
    __shared__ int lds[256];
    lds[tid] = s;
    __syncthreads();
    for (int off = 1; off < 256; off <<= 1) {
        int t = (tid >= off) ? lds[tid - off] : 0;
        __syncthreads();
        lds[tid] += t;
        __syncthreads();
    }
    int prefix = bsum[blockIdx.x] + lds[tid] - s;
#pragma unroll
    for (int k = 0; k < 4; ++k) {
        int idx = base + k;
        if (idx < N_NODES) { offs[idx] = prefix; cur[idx] = prefix; }
        prefix += v[k];
    }
    if (blockIdx.x == 0 && tid == 0) { off_sc[N_NODES] = N_EDGES; off_fc[N_NODES] = N_EDGES; }
}

// ---- direct CSR scatter (round-3-proven pattern; srcs only, en eliminated) ----
__global__ void build2_kernel(const int* __restrict__ sc_ei, const int* __restrict__ fc_ei,
                              int* __restrict__ cur_sc, int* __restrict__ cur_fc,
                              int* __restrict__ srcs_sc, int* __restrict__ srcs_fc) {
    int b = blockIdx.x;
    int branch = b >= EB;
    const int* ei = branch ? fc_ei : sc_ei;
    int* cur  = branch ? cur_fc : cur_sc;
    int* srcs = branch ? srcs_fc : srcs_sc;
    int e = (branch ? b - EB : b) * 256 + threadIdx.x;
    if (e >= N_EDGES) return;
    int s = ei[e], d = ei[N_EDGES + e];
    int pos = atomicAdd(&cur[d], 1);
    srcs[pos] = s;
}

// ---- pre-convert+transpose weights: Wt[l'][n][k] = W[l][k][n] (bf16), l' = branch*3+l ----
__global__ void convert_w_kernel(const float* __restrict__ sc_W, const float* __restrict__ fc_W,
                                 u16* __restrict__ Wt) {
    int idx = blockIdx.x * 256 + threadIdx.x;  // 6*16384 total
    if (idx >= 6 * 16384) return;
    int lp = idx >> 14;
    int r = idx & 16383;
    int n = r >> 7, k = r & 127;
    const float* W = (lp >= 3) ? fc_W : sc_W;
    int l = (lp >= 3) ? lp - 3 : lp;
    Wt[idx] = f2b(W[(size_t)l * 16384 + k * 128 + n]);
}

// ============================= MFMA GEMM: H'[n] = (bf16(A[n]) @ W) * dis[n] =============================
__global__ __launch_bounds__(256) void gemm2_kernel(
        const void* __restrict__ A_sc, const void* __restrict__ A_fc, int a_fp32,
        const u16* __restrict__ Wt, int layer,
        const float* __restrict__ d_sc, const float* __restrict__ d_fc,
        u16* __restrict__ H_sc, u16* __restrict__ H_fc) {
    int branch = blockIdx.x >= GB;
    int blk = branch ? blockIdx.x - GB : blockIdx.x;
    const void* A = branch ? A_fc : A_sc;
    const float* dis = branch ? d_fc : d_sc;
    u16* H = branch ? H_fc : H_sc;
    const u16* W = Wt + (((size_t)branch * 3 + layer) << 14);

    __shared__ u16 Alds[64 * 136];   // rows padded to 136 u16 (272 B)
    __shared__ u16 Wlds[128 * 136];  // Wt rows: n-major, k contiguous
    const int tid = threadIdx.x;
    const int row0 = blk * 64;

    if (a_fp32) {
        const float* Af = (const float*)A;
#pragma unroll
        for (int i = 0; i < 8; ++i) {
            int idx = tid + i * 256;
            int r = idx >> 5, f = idx & 31;
            int grow = row0 + r;
            float4 v = (grow < N_NODES) ? *(const float4*)&Af[(size_t)grow * 128 + f * 4]
                                        : make_float4(0.f, 0.f, 0.f, 0.f);
            ushort4 o;
            o.x = f2b(v.x); o.y = f2b(v.y); o.z = f2b(v.z); o.w = f2b(v.w);
            *(ushort4*)&Alds[r * 136 + f * 4] = o;
        }
    } else {
        const u16* Ab = (const u16*)A;
#pragma unroll
        for (int i = 0; i < 4; ++i) {
            int idx = tid + i * 256;
            int r = idx >> 4, f = idx & 15;
            int grow = row0 + r;
            u16x8 v = {};
            if (grow < N_NODES) v = *(const u16x8*)&Ab[(size_t)grow * 128 + f * 8];
            *(u16x8*)&Alds[r * 136 + f * 8] = v;
        }
    }
#pragma unroll
    for (int i = 0; i < 8; ++i) {
        int idx = tid + i * 256;
        int n = idx >> 4, f = idx & 15;
        *(u16x8*)&Wlds[n * 136 + f * 8] = *(const u16x8*)&W[n * 128 + f * 8];
    }
    __syncthreads();

    const int wv = tid >> 6;
    const int lane = tid & 63;
    const int m = lane & 15;       // row (A) / col (B) within 16-tile
    const int quad = lane >> 4;    // k-subchunk

    bf16x8 af[4];
#pragma unroll
    for (int kt = 0; kt < 4; ++kt)
        af[kt] = *(const bf16x8*)&Alds[(wv * 16 + m) * 136 + kt * 32 + quad * 8];

    f32x4 acc[8];
#pragma unroll
    for (int ct = 0; ct < 8; ++ct) { acc[ct][0] = 0.f; acc[ct][1] = 0.f; acc[ct][2] = 0.f; acc[ct][3] = 0.f; }

#pragma unroll
    for (int ct = 0; ct < 8; ++ct) {
#pragma unroll
        for (int kt = 0; kt < 4; ++kt) {
            bf16x8 bf = *(const bf16x8*)&Wlds[(ct * 16 + m) * 136 + kt * 32 + quad * 8];
            acc[ct] = __builtin_amdgcn_mfma_f32_16x16x32_bf16(af[kt], bf, acc[ct], 0, 0, 0);
        }
    }

    // fold dis: rows quad*4..quad*4+3 of this wave's 16-row tile (contiguous -> float4)
    float4 dv = *(const float4*)&dis[row0 + wv * 16 + quad * 4];  // ws-padded, OOB-safe
#pragma unroll
    for (int ct = 0; ct < 8; ++ct) {
        acc[ct][0] *= dv.x; acc[ct][1] *= dv.y; acc[ct][2] *= dv.z; acc[ct][3] *= dv.w;
    }

    // epilogue: C/D layout col=lane&15, row=quad*4+reg -> LDS -> coalesced bf16 stores
#pragma unroll
    for (int ct = 0; ct < 8; ++ct)
#pragma unroll
        for (int r = 0; r < 4; ++r)
            Alds[(wv * 16 + quad * 4 + r) * 136 + ct * 16 + m] = f2b(acc[ct][r]);
    __syncthreads();
#pragma unroll
    for (int i = 0; i < 4; ++i) {
        int idx = i * 64 + lane;
        int r = idx >> 4, f = idx & 15;
        int grow = row0 + wv * 16 + r;
        if (grow < N_NODES)
            *(u16x8*)&H[(size_t)grow * 128 + f * 8] = *(const u16x8*)&Alds[(wv * 16 + r) * 136 + f * 8];
    }
}

// ============================= GCN aggregation: x[n] = relu(dis[n]*(sum h'[src] + h'[n]) + b) =============================
__global__ __launch_bounds__(256) void gather2_kernel(
        const u16* __restrict__ h_sc, const u16* __restrict__ h_fc,
        const int* __restrict__ srcs_sc, const int* __restrict__ srcs_fc,
        const int* __restrict__ off_sc, const int* __restrict__ off_fc,
        const float* __restrict__ d_sc, const float* __restrict__ d_fc,
        const float* __restrict__ b_sc, const float* __restrict__ b_fc,
        u16* __restrict__ x_sc, u16* __restrict__ x_fc) {
    int bb = blockIdx.x;
    int branch = bb >= GAT_NB;
    if (branch) bb -= GAT_NB;
    const u16* h    = branch ? h_fc : h_sc;
    const int* srcs = branch ? srcs_fc : srcs_sc;
    const int* offs = branch ? off_fc : off_sc;
    const float* dis = branch ? d_fc : d_sc;
    const float* bias = branch ? b_fc : b_sc;
    u16* xout = branch ? x_fc : x_sc;

    int node = bb * 4 + (threadIdx.x >> 6);
    int lane = threadIdx.x & 63;
    int half = lane >> 5;           // which edge of a pair this half-wave owns
    int c = (lane & 31) * 4;        // feature chunk
    int beg = offs[node], end = offs[node + 1];
    float ax = 0.f, ay = 0.f, az = 0.f, aw = 0.f;
    int j = beg + half;
    for (; j + 2 < end; j += 4) {
        int s0 = srcs[j], s1 = srcs[j + 2];
        ushort4 v0 = *(const ushort4*)&h[(size_t)s0 * 128 + c];
        ushort4 v1 = *(const ushort4*)&h[(size_t)s1 * 128 + c];
        ax += b2f(v0.x) + b2f(v1.x);
        ay += b2f(v0.y) + b2f(v1.y);
        az += b2f(v0.z) + b2f(v1.z);
        aw += b2f(v0.w) + b2f(v1.w);
    }
    if (j < end) {
        int s0 = srcs[j];
        ushort4 v0 = *(const ushort4*)&h[(size_t)s0 * 128 + c];
        ax += b2f(v0.x);
        ay += b2f(v0.y);
        az += b2f(v0.z);
        aw += b2f(v0.w);
    }
    ax += __shfl_xor(ax, 32);
    ay += __shfl_xor(ay, 32);
    az += __shfl_xor(az, 32);
    aw += __shfl_xor(aw, 32);
    if (half == 0) {
        float dn = dis[node];
        ushort4 hv = *(const ushort4*)&h[(size_t)node * 128 + c];  // h' self row
        float4 b4 = *(const float4*)&bias[c];
        ushort4 o;
        o.x = f2b(fmaxf(dn * (ax + b2f(hv.x)) + b4.x, 0.f));
        o.y = f2b(fmaxf(dn * (ay + b2f(hv.y)) + b4.y, 0.f));
        o.z = f2b(fmaxf(dn * (az + b2f(hv.z)) + b4.z, 0.f));
        o.w = f2b(fmaxf(dn * (aw + b2f(hv.w)) + b4.w, 0.f));
        *(ushort4*)&xout[(size_t)node * 128 + c] = o;
    }
}

// ============================= pooling (batch is sorted; x is bf16, fp32 accumulate) =============================
__global__ __launch_bounds__(128) void pool2_kernel(const u16* __restrict__ x_sc,
                                                    const u16* __restrict__ x_fc,
                                                    const int* __restrict__ batch,
                                                    float* __restrict__ g_sc,
                                                    float* __restrict__ g_fc) {
    int b = blockIdx.x;
    const u16* x = (b >= PB) ? x_fc : x_sc;
    float* g     = (b >= PB) ? g_fc : g_sc;
    int blk = (b >= PB) ? b - PB : b;
    int c = threadIdx.x;
    int start = blk * 64;
    if (start >= N_NODES) return;
    int endn = min(start + 64, N_NODES);
    float acc = 0.f;
    int cur = batch[start];
    for (int i = start; i < endn; ++i) {
        int bb = batch[i];
        if (bb != cur) {
            atomicAdd(&g[(size_t)cur * 128 + c], acc);
            acc = 0.f;
            cur = bb;
        }
        acc += b2f(x[(size_t)i * 128 + c]);
    }
    atomicAdd(&g[(size_t)cur * 128 + c], acc);
}

// ============================= row L2-normalize =============================
__global__ __launch_bounds__(64) void normalize_kernel(const float* __restrict__ g_sc,
                                                       const float* __restrict__ g_fc,
                                                       float* __restrict__ n_sc,
                                                       float* __restrict__ n_fc) {
    int r = blockIdx.x & 255;
    const float* g = (blockIdx.x < 256) ? g_sc : g_fc;
    float* o = (blockIdx.x < 256) ? n_sc : n_fc;
    int c = threadIdx.x;
    float v0 = g[r * 128 + c], v1 = g[r * 128 + c + 64];
    float ss = v0 * v0 + v1 * v1;
#pragma unroll
    for (int off = 32; off; off >>= 1) ss += __shfl_xor(ss, off);
    float inv = 1.0f / fmaxf(sqrtf(ss), 1e-12f);
    o[r * 128 + c] = v0 * inv;
    o[r * 128 + c + 64] = v1 * inv;
}

// ============================= classifier head =============================
__global__ __launch_bounds__(128) void head_kernel(const float* __restrict__ g_sc,
                                                   const float* __restrict__ g_fc,
                                                   const float* __restrict__ W1,
                                                   const float* __restrict__ b1,
                                                   const float* __restrict__ W2,
                                                   const float* __restrict__ b2,
                                                   float* __restrict__ out) {
    __shared__ float cat[256];
    __shared__ float red[4];
    int i = blockIdx.x, c = threadIdx.x;
    cat[c] = g_sc[i * 128 + c];
    cat[128 + c] = g_fc[i * 128 + c];
    __syncthreads();
    float acc = b1[c];
    for (int k = 0; k < 256; ++k) acc += cat[k] * W1[k * 128 + c];
    float z = fmaxf(acc, 0.f);
    float l0 = z * W2[c * 2 + 0];
    float l1 = z * W2[c * 2 + 1];
#pragma unroll
    for (int off = 32; off; off >>= 1) {
        l0 += __shfl_xor(l0, off);
        l1 += __shfl_xor(l1, off);
    }
    if ((c & 63) == 0) {
        red[(c >> 6) * 2 + 0] = l0;
        red[(c >> 6) * 2 + 1] = l1;
    }
    __syncthreads();
    if (c == 0) {
        float L0 = red[0] + red[2] + b2[0];
        float L1 = red[1] + red[3] + b2[1];
        float m = fmaxf(L0, L1);
        float lse = m + logf(expf(L0 - m) + expf(L1 - m));
        out[i * 2 + 0] = L0 - lse;
        out[i * 2 + 1] = L1 - lse;
    }
}

// ============================= contrastive loss =============================
__global__ __launch_bounds__(256) void contrast_kernel(const float* __restrict__ n_sc,
                                                       const float* __restrict__ n_fc,
                                                       float* __restrict__ loss_acc) {
    __shared__ float arow[128];
    __shared__ float redm[4];
    __shared__ float reds[4];
    __shared__ float diag_s;
    int b = blockIdx.x;
    int i = b & 255;
    bool which = b >= 256;
    const float* A  = which ? n_fc : n_sc;
    const float* B1 = which ? n_sc : n_fc;
    const float* B2 = which ? n_fc : n_sc;
    int j = threadIdx.x;
    if (j < 128) arow[j] = A[i * 128 + j];
    __syncthreads();
    float d1 = 0.f, d2 = 0.f;
    for (int k = 0; k < 128; ++k) {
        float a = arow[k];
        d1 += a * B1[(size_t)j * 128 + k];
        d2 += a * B2[(size_t)j * 128 + k];
    }
    const float t = 2.0f;  // 1/TEMPERATURE
    float v1 = t * d1;
    float v2 = (j == i) ? 0.0f : 0.8f * t * d2;
    if (j == i) diag_s = v1;
    float m = fmaxf(v1, v2);
#pragma unroll
    for (int off = 32; off; off >>= 1) m = fmaxf(m, __shfl_xor(m, off));
    if ((j & 63) == 0) redm[j >> 6] = m;
    __syncthreads();
    m = fmaxf(fmaxf(redm[0], redm[1]), fmaxf(redm[2], redm[3]));
    float s = expf(v1 - m) + expf(v2 - m);
#pragma unroll
    for (int off = 32; off; off >>= 1) s += __shfl_xor(s, off);
    if ((j & 63) == 0) reds[j >> 6] = s;
    __syncthreads();
    if (j == 0) {
        float S = reds[0] + reds[1] + reds[2] + reds[3];
        float lse = m + logf(S);
        atomicAdd(loss_acc, lse - diag_s);
    }
}

__global__ void final_add(float* __restrict__ out, const float* __restrict__ loss) {
    int t = threadIdx.x;
    if (t < 512) out[t] += loss[0] * (1.0f / 512.0f);
}

// ============================= launch =============================

extern "C" void kernel_launch(void* const* d_in, const int* in_sizes, int n_in,
                              void* d_out, int out_size, void* d_ws, size_t ws_size,
                              hipStream_t stream) {
    const float* sc_x  = (const float*)d_in[0];
    const float* fc_x  = (const float*)d_in[1];
    const int*   sc_ei = (const int*)d_in[2];
    const int*   fc_ei = (const int*)d_in[3];
    const int*   batch = (const int*)d_in[4];
    const float* sc_W  = (const float*)d_in[5];
    const float* sc_b  = (const float*)d_in[6];
    const float* fc_W  = (const float*)d_in[7];
    const float* fc_b  = (const float*)d_in[8];
    const float* fc1_W = (const float*)d_in[9];
    const float* fc1_b = (const float*)d_in[10];
    const float* fc2_W = (const float*)d_in[11];
    const float* fc2_b = (const float*)d_in[12];
    float* out = (float*)d_out;

    const size_t NF = (size_t)N_NODES * HID;  // 12.8M elements

    float* ws = (float*)d_ws;
    float* dis_sc = ws;                // N f32 (gemm epilogue float4 reads padded by dis_fc)
    float* dis_fc = dis_sc + N_NODES;  // N f32 (padded by g arrays after)
    float* g_sc  = dis_fc + N_NODES;   // g_sc,g_fc contiguous for one memset
    float* g_fc  = g_sc + NGRAPH * HID;
    float* n_sc  = g_fc + NGRAPH * HID;
    float* n_fc  = n_sc + NGRAPH * HID;
    float* lossp = n_fc + NGRAPH * HID;  // 1 (+pad)
    u16* h_sc    = (u16*)(lossp + 4);    // NF bf16 (h' = h*dis)
    u16* h_fc    = h_sc + NF;
    u16* x_sc    = h_fc + NF;            // NF bf16 activations
    u16* x_fc    = x_sc + NF;
    u16* Wtb     = x_fc + NF;            // 6*16384 bf16 (transposed weights)
    int* srcs_sc   = (int*)(Wtb + 6 * 16384);  // E
    int* srcs_fc   = srcs_sc + N_EDGES;
    int* counts_sc = srcs_fc + N_EDGES;  // N (contiguous pair for memset)
    int* counts_fc = counts_sc + N_NODES;
    int* off_sc    = counts_fc + N_NODES;  // N+1
    int* off_fc    = off_sc + (N_NODES + 1);
    int* cur_sc    = off_fc + (N_NODES + 1);  // N
    int* cur_fc    = cur_sc + N_NODES;
    int* bsum      = cur_fc + N_NODES;        // 2*NCHUNK
    (void)ws_size; (void)n_in; (void)in_sizes; (void)out_size;

    // ---- CSR build (direct per-node-cursor scatter, both branches per dispatch) ----
    hipMemsetAsync(counts_sc, 0, 2 * N_NODES * sizeof(int), stream);
    count2_kernel<<<2 * EB, 256, 0, stream>>>(sc_ei, fc_ei, counts_sc, counts_fc);
    dis2_kernel<<<2 * NB, 256, 0, stream>>>(counts_sc, counts_fc, dis_sc, dis_fc);
    block_sum_kernel<<<2 * NCHUNK, 256, 0, stream>>>(counts_sc, counts_fc, bsum);
    scan_tops_kernel<<<1, 256, 0, stream>>>(bsum);
    scan_final_kernel<<<2 * NCHUNK, 256, 0, stream>>>(counts_sc, counts_fc, bsum,
                                                      off_sc, off_fc, cur_sc, cur_fc);
    build2_kernel<<<2 * EB, 256, 0, stream>>>(sc_ei, fc_ei, cur_sc, cur_fc, srcs_sc, srcs_fc);
    convert_w_kernel<<<(6 * 16384 + 255) / 256, 256, 0, stream>>>(sc_W, fc_W, Wtb);

    // ---- 3 GCN layers, both branches per launch ----
    for (int l = 0; l < 3; ++l) {
        const void* a_sc = (l == 0) ? (const void*)sc_x : (const void*)x_sc;
        const void* a_fc = (l == 0) ? (const void*)fc_x : (const void*)x_fc;
        gemm2_kernel<<<2 * GB, 256, 0, stream>>>(a_sc, a_fc, (l == 0) ? 1 : 0, Wtb, l,
                                                 dis_sc, dis_fc, h_sc, h_fc);
        gather2_kernel<<<2 * GAT_NB, 256, 0, stream>>>(
            h_sc, h_fc, srcs_sc, srcs_fc, off_sc, off_fc,
            dis_sc, dis_fc, sc_b + (size_t)l * HID, fc_b + (size_t)l * HID, x_sc, x_fc);
    }

    // ---- pooling ----
    hipMemsetAsync(g_sc, 0, 2 * NGRAPH * HID * sizeof(float), stream);
    pool2_kernel<<<2 * PB, 128, 0, stream>>>(x_sc, x_fc, batch, g_sc, g_fc);

    // ---- head + contrastive ----
    normalize_kernel<<<512, 64, 0, stream>>>(g_sc, g_fc, n_sc, n_fc);
    head_kernel<<<NGRAPH, 128, 0, stream>>>(g_sc, g_fc, fc1_W, fc1_b, fc2_W, fc2_b, out);
    hipMemsetAsync(lossp, 0, sizeof(float), stream);
    contrast_kernel<<<512, 256, 0, stream>>>(n_sc, n_fc, lossp);
    final_add<<<1, 512, 0, stream>>>(out, lossp);
}

// Round 10
// 1137.327 us; speedup vs baseline: 2.2121x; 1.0097x over previous
//
#include <hip/hip_runtime.h>
#include <math.h>

#define N_NODES 100000
#define N_EDGES 1600000
#define HID     128
#define NGRAPH  256
#define SCHUNK  1024
#define NCHUNK  ((N_NODES + SCHUNK - 1) / SCHUNK)   // 98
#define GB      ((N_NODES + 63) / 64)               // 1563 gemm blocks per branch
#define GAT_NB  (N_NODES / 4)                       // 25000 gather blocks per branch
#define EB      ((N_EDGES + 255) / 256)             // 6250
#define NB      ((N_NODES + 255) / 256)             // 391
#define PB      ((N_NODES + 63) / 64)               // 1563 pool blocks per branch

typedef unsigned short u16;
typedef unsigned int   u32;
typedef __attribute__((ext_vector_type(8))) short    bf16x8;
typedef __attribute__((ext_vector_type(4))) float    f32x4;
typedef __attribute__((ext_vector_type(8))) unsigned short u16x8;

__device__ inline float b2f(u16 u) {
    union { unsigned int i; float f; } x; x.i = ((unsigned int)u) << 16; return x.f;
}
__device__ inline u16 f2b(float f) {
    union { float f; unsigned int i; } x; x.f = f;
    unsigned int r = x.i + 0x7fff + ((x.i >> 16) & 1);   // round-to-nearest-even
    return (u16)(r >> 16);
}

// ============================= setup kernels =============================

__global__ void count2_kernel(const int* __restrict__ sc_ei, const int* __restrict__ fc_ei,
                              int* __restrict__ c_sc, int* __restrict__ c_fc) {
    int b = blockIdx.x;
    const int* ei = (b >= EB) ? fc_ei : sc_ei;
    int* counts   = (b >= EB) ? c_fc  : c_sc;
    int e = (b >= EB ? b - EB : b) * 256 + threadIdx.x;
    if (e < N_EDGES) atomicAdd(&counts[ei[N_EDGES + e]], 1);
}

__global__ void dis2_kernel(const int* __restrict__ c_sc, const int* __restrict__ c_fc,
                            float* __restrict__ d_sc, float* __restrict__ d_fc) {
    int b = blockIdx.x;
    const int* counts = (b >= NB) ? c_fc : c_sc;
    float* dis        = (b >= NB) ? d_fc : d_sc;
    int i = (b >= NB ? b - NB : b) * 256 + threadIdx.x;
    if (i < N_NODES) dis[i] = rsqrtf((float)counts[i] + 1.0f);
}

// ---- 3-phase multi-block exclusive scan (both branches in one grid) ----
__global__ __launch_bounds__(256) void block_sum_kernel(const int* __restrict__ c_sc,
                                                        const int* __restrict__ c_fc,
                                                        int* __restrict__ bsum) {
    int branch = blockIdx.x / NCHUNK;
    int chunk  = blockIdx.x % NCHUNK;
    const int* counts = branch ? c_fc : c_sc;
    int base = chunk * SCHUNK;
    int tid = threadIdx.x;
    int v = 0;
    for (int i = tid; i < SCHUNK; i += 256) {
        int idx = base + i;
        if (idx < N_NODES) v += counts[idx];
    }
    __shared__ int red[4];
#pragma unroll
    for (int off = 32; off; off >>= 1) v += __shfl_down(v, off);
    if ((tid & 63) == 0) red[tid >> 6] = v;
    __syncthreads();
    if (tid == 0) bsum[blockIdx.x] = red[0] + red[1] + red[2] + red[3];
}

__global__ __launch_bounds__(256) void scan_tops_kernel(int* __restrict__ bsum) {
    __shared__ int lds[2][128];
    int tid = threadIdx.x;
    int branch = tid >> 7;
    int i = tid & 127;
    int orig = (i < NCHUNK) ? bsum[branch * NCHUNK + i] : 0;
    lds[branch][i] = orig;
    __syncthreads();
    for (int off = 1; off < 128; off <<= 1) {
        int t = (i >= off) ? lds[branch][i - off] : 0;
        __syncthreads();
        lds[branch][i] += t;
        __syncthreads();
    }
    if (i < NCHUNK) bsum[branch * NCHUNK + i] = lds[branch][i] - orig;  // exclusive
}

__global__ __launch_bounds__(256) void scan_final_kernel(
        const int* __restrict__ c_sc, const int* __restrict__ c_fc,
        const int* __restrict__ bsum,
        int* __restrict__ off_sc, int* __restrict__ off_fc,
        int* __restrict__ cur_sc, int* __restrict__ cur_fc) {
    int branch = blockIdx.x / NCHUNK;
    int chunk  = blockIdx.x % NCHUNK;
    const int* counts = branch ? c_fc : c_sc;
    int* offs = branch ? off_fc : off_sc;
    int* cur  = branch ? cur_fc : cur_sc;
    int tid = threadIdx.x;
    int base = chunk * SCHUNK + tid * 4;
    int v[4], s = 0;
#pragma unroll
    for (int k = 0; k < 4; ++k) {
        int idx = base + k;
        v[k] = (idx < N_NODES) ? counts[idx] : 0;
        s += v[k];
    }
    __shared__ int lds[256];
    lds[tid] = s;
    __syncthreads();
    for (int off = 1; off < 256; off <<= 1) {
        int t = (tid >= off) ? lds[tid - off] : 0;
        __syncthreads();
        lds[tid] += t;
        __syncthreads();
    }
    int prefix = bsum[blockIdx.x] + lds[tid] - s;
#pragma unroll
    for (int k = 0; k < 4; ++k) {
        int idx = base + k;
        if (idx < N_NODES) { offs[idx] = prefix; cur[idx] = prefix; }
        prefix += v[k];
    }
    if (blockIdx.x == 0 && tid == 0) { off_sc[N_NODES] = N_EDGES; off_fc[N_NODES] = N_EDGES; }
}

// ---- direct CSR scatter (round-3/7-proven pattern; srcs only, en eliminated) ----
__global__ void build2_kernel(const int* __restrict__ sc_ei, const int* __restrict__ fc_ei,
                              int* __restrict__ cur_sc, int* __restrict__ cur_fc,
                              int* __restrict__ srcs_sc, int* __restrict__ srcs_fc) {
    int b = blockIdx.x;
    int branch = b >= EB;
    const int* ei = branch ? fc_ei : sc_ei;
    int* cur  = branch ? cur_fc : cur_sc;
    int* srcs = branch ? srcs_fc : srcs_sc;
    int e = (branch ? b - EB : b) * 256 + threadIdx.x;
    if (e >= N_EDGES) return;
    int s = ei[e], d = ei[N_EDGES + e];
    int pos = atomicAdd(&cur[d], 1);
    srcs[pos] = s;
}

// ---- pre-convert+transpose weights: Wt[l'][n][k] = W[l][k][n] (bf16), l' = branch*3+l ----
__global__ void convert_w_kernel(const float* __restrict__ sc_W, const float* __restrict__ fc_W,
                                 u16* __restrict__ Wt) {
    int idx = blockIdx.x * 256 + threadIdx.x;  // 6*16384 total
    if (idx >= 6 * 16384) return;
    int lp = idx >> 14;
    int r = idx & 16383;
    int n = r >> 7, k = r & 127;
    const float* W = (lp >= 3) ? fc_W : sc_W;
    int l = (lp >= 3) ? lp - 3 : lp;
    Wt[idx] = f2b(W[(size_t)l * 16384 + k * 128 + n]);
}

// ============================= MFMA GEMM: H'[n] = (bf16(A[n]) @ W) * dis[n] =============================
__global__ __launch_bounds__(256) void gemm2_kernel(
        const void* __restrict__ A_sc, const void* __restrict__ A_fc, int a_fp32,
        const u16* __restrict__ Wt, int layer,
        const float* __restrict__ d_sc, const float* __restrict__ d_fc,
        u16* __restrict__ H_sc, u16* __restrict__ H_fc) {
    int branch = blockIdx.x >= GB;
    int blk = branch ? blockIdx.x - GB : blockIdx.x;
    const void* A = branch ? A_fc : A_sc;
    const float* dis = branch ? d_fc : d_sc;
    u16* H = branch ? H_fc : H_sc;
    const u16* W = Wt + (((size_t)branch * 3 + layer) << 14);

    __shared__ u16 Alds[64 * 136];   // rows padded to 136 u16 (272 B)
    __shared__ u16 Wlds[128 * 136];  // Wt rows: n-major, k contiguous
    const int tid = threadIdx.x;
    const int row0 = blk * 64;

    if (a_fp32) {
        const float* Af = (const float*)A;
#pragma unroll
        for (int i = 0; i < 8; ++i) {
            int idx = tid + i * 256;
            int r = idx >> 5, f = idx & 31;
            int grow = row0 + r;
            float4 v = (grow < N_NODES) ? *(const float4*)&Af[(size_t)grow * 128 + f * 4]
                                        : make_float4(0.f, 0.f, 0.f, 0.f);
            ushort4 o;
            o.x = f2b(v.x); o.y = f2b(v.y); o.z = f2b(v.z); o.w = f2b(v.w);
            *(ushort4*)&Alds[r * 136 + f * 4] = o;
        }
    } else {
        const u16* Ab = (const u16*)A;
#pragma unroll
        for (int i = 0; i < 4; ++i) {
            int idx = tid + i * 256;
            int r = idx >> 4, f = idx & 15;
            int grow = row0 + r;
            u16x8 v = {};
            if (grow < N_NODES) v = *(const u16x8*)&Ab[(size_t)grow * 128 + f * 8];
            *(u16x8*)&Alds[r * 136 + f * 8] = v;
        }
    }
#pragma unroll
    for (int i = 0; i < 8; ++i) {
        int idx = tid + i * 256;
        int n = idx >> 4, f = idx & 15;
        *(u16x8*)&Wlds[n * 136 + f * 8] = *(const u16x8*)&W[n * 128 + f * 8];
    }
    __syncthreads();

    const int wv = tid >> 6;
    const int lane = tid & 63;
    const int m = lane & 15;       // row (A) / col (B) within 16-tile
    const int quad = lane >> 4;    // k-subchunk

    bf16x8 af[4];
#pragma unroll
    for (int kt = 0; kt < 4; ++kt)
        af[kt] = *(const bf16x8*)&Alds[(wv * 16 + m) * 136 + kt * 32 + quad * 8];

    f32x4 acc[8];
#pragma unroll
    for (int ct = 0; ct < 8; ++ct) { acc[ct][0] = 0.f; acc[ct][1] = 0.f; acc[ct][2] = 0.f; acc[ct][3] = 0.f; }

#pragma unroll
    for (int ct = 0; ct < 8; ++ct) {
#pragma unroll
        for (int kt = 0; kt < 4; ++kt) {
            bf16x8 bf = *(const bf16x8*)&Wlds[(ct * 16 + m) * 136 + kt * 32 + quad * 8];
            acc[ct] = __builtin_amdgcn_mfma_f32_16x16x32_bf16(af[kt], bf, acc[ct], 0, 0, 0);
        }
    }

    // fold dis: rows quad*4..quad*4+3 of this wave's 16-row tile (contiguous -> float4)
    float4 dv = *(const float4*)&dis[row0 + wv * 16 + quad * 4];  // ws-padded, OOB-safe
#pragma unroll
    for (int ct = 0; ct < 8; ++ct) {
        acc[ct][0] *= dv.x; acc[ct][1] *= dv.y; acc[ct][2] *= dv.z; acc[ct][3] *= dv.w;
    }

    // epilogue: C/D layout col=lane&15, row=quad*4+reg -> LDS -> coalesced bf16 stores
#pragma unroll
    for (int ct = 0; ct < 8; ++ct)
#pragma unroll
        for (int r = 0; r < 4; ++r)
            Alds[(wv * 16 + quad * 4 + r) * 136 + ct * 16 + m] = f2b(acc[ct][r]);
    __syncthreads();
#pragma unroll
    for (int i = 0; i < 4; ++i) {
        int idx = i * 64 + lane;
        int r = idx >> 4, f = idx & 15;
        int grow = row0 + wv * 16 + r;
        if (grow < N_NODES)
            *(u16x8*)&H[(size_t)grow * 128 + f * 8] = *(const u16x8*)&Alds[(wv * 16 + r) * 136 + f * 8];
    }
}

// ============================= GCN aggregation: x[n] = relu(dis[n]*(sum h'[src] + h'[n]) + b) =============================
// Wave per node; QUARTER-wave (16 lanes x u16x8 = full 256B row) per edge, 2-way unroll
// -> 8 row-loads in flight per wave (2x the prior half-wave scheme) for latency hiding.
__global__ __launch_bounds__(256) void gather2_kernel(
        const u16* __restrict__ h_sc, const u16* __restrict__ h_fc,
        const int* __restrict__ srcs_sc, const int* __restrict__ srcs_fc,
        const int* __restrict__ off_sc, const int* __restrict__ off_fc,
        const float* __restrict__ d_sc, const float* __restrict__ d_fc,
        const float* __restrict__ b_sc, const float* __restrict__ b_fc,
        u16* __restrict__ x_sc, u16* __restrict__ x_fc) {
    int bb = blockIdx.x;
    int branch = bb >= GAT_NB;
    if (branch) bb -= GAT_NB;
    const u16* h    = branch ? h_fc : h_sc;
    const int* srcs = branch ? srcs_fc : srcs_sc;
    const int* offs = branch ? off_fc : off_sc;
    const float* dis = branch ? d_fc : d_sc;
    const float* bias = branch ? b_fc : b_sc;
    u16* xout = branch ? x_fc : x_sc;

    int node = bb * 4 + (threadIdx.x >> 6);
    int lane = threadIdx.x & 63;
    int quarter = lane >> 4;        // 0..3: which edge of each group of 4 this quarter owns
    int c = (lane & 15) * 8;        // feature chunk of 8 bf16 (16B)
    int beg = offs[node], end = offs[node + 1];
    float acc[8] = {0.f, 0.f, 0.f, 0.f, 0.f, 0.f, 0.f, 0.f};
    int j = beg + quarter;
    // 2 edges in flight per quarter => 8 per wave
    for (; j + 4 < end; j += 8) {
        int s0 = srcs[j], s1 = srcs[j + 4];
        u16x8 v0 = *(const u16x8*)&h[(size_t)s0 * 128 + c];
        u16x8 v1 = *(const u16x8*)&h[(size_t)s1 * 128 + c];
#pragma unroll
        for (int t = 0; t < 8; ++t) acc[t] += b2f(v0[t]) + b2f(v1[t]);
    }
    if (j < end) {
        int s0 = srcs[j];
        u16x8 v0 = *(const u16x8*)&h[(size_t)s0 * 128 + c];
#pragma unroll
        for (int t = 0; t < 8; ++t) acc[t] += b2f(v0[t]);
    }
#pragma unroll
    for (int t = 0; t < 8; ++t) {
        acc[t] += __shfl_xor(acc[t], 16);
        acc[t] += __shfl_xor(acc[t], 32);
    }
    if (quarter == 0) {
        float dn = dis[node];
        u16x8 hv = *(const u16x8*)&h[(size_t)node * 128 + c];  // h' self row
        float4 b0 = *(const float4*)&bias[c];
        float4 b1 = *(const float4*)&bias[c + 4];
        float bv[8] = {b0.x, b0.y, b0.z, b0.w, b1.x, b1.y, b1.z, b1.w};
        u16x8 o;
#pragma unroll
        for (int t = 0; t < 8; ++t)
            o[t] = f2b(fmaxf(dn * (acc[t] + b2f(hv[t])) + bv[t], 0.f));
        *(u16x8*)&xout[(size_t)node * 128 + c] = o;
    }
}

// ============================= pooling (batch is sorted; x is bf16, fp32 accumulate) =============================
__global__ __launch_bounds__(128) void pool2_kernel(const u16* __restrict__ x_sc,
                                                    const u16* __restrict__ x_fc,
                                                    const int* __restrict__ batch,
                                                    float* __restrict__ g_sc,
                                                    float* __restrict__ g_fc) {
    int b = blockIdx.x;
    const u16* x = (b >= PB) ? x_fc : x_sc;
    float* g     = (b >= PB) ? g_fc : g_sc;
    int blk = (b >= PB) ? b - PB : b;
    int c = threadIdx.x;
    int start = blk * 64;
    if (start >= N_NODES) return;
    int endn = min(start + 64, N_NODES);
    float acc = 0.f;
    int cur = batch[start];
    for (int i = start; i < endn; ++i) {
        int bb = batch[i];
        if (bb != cur) {
            atomicAdd(&g[(size_t)cur * 128 + c], acc);
            acc = 0.f;
            cur = bb;
        }
        acc += b2f(x[(size_t)i * 128 + c]);
    }
    atomicAdd(&g[(size_t)cur * 128 + c], acc);
}

// ============================= row L2-normalize =============================
__global__ __launch_bounds__(64) void normalize_kernel(const float* __restrict__ g_sc,
                                                       const float* __restrict__ g_fc,
                                                       float* __restrict__ n_sc,
                                                       float* __restrict__ n_fc) {
    int r = blockIdx.x & 255;
    const float* g = (blockIdx.x < 256) ? g_sc : g_fc;
    float* o = (blockIdx.x < 256) ? n_sc : n_fc;
    int c = threadIdx.x;
    float v0 = g[r * 128 + c], v1 = g[r * 128 + c + 64];
    float ss = v0 * v0 + v1 * v1;
#pragma unroll
    for (int off = 32; off; off >>= 1) ss += __shfl_xor(ss, off);
    float inv = 1.0f / fmaxf(sqrtf(ss), 1e-12f);
    o[r * 128 + c] = v0 * inv;
    o[r * 128 + c + 64] = v1 * inv;
}

// ============================= classifier head =============================
__global__ __launch_bounds__(128) void head_kernel(const float* __restrict__ g_sc,
                                                   const float* __restrict__ g_fc,
                                                   const float* __restrict__ W1,
                                                   const float* __restrict__ b1,
                                                   const float* __restrict__ W2,
                                                   const float* __restrict__ b2,
                                                   float* __restrict__ out) {
    __shared__ float cat[256];
    __shared__ float red[4];
    int i = blockIdx.x, c = threadIdx.x;
    cat[c] = g_sc[i * 128 + c];
    cat[128 + c] = g_fc[i * 128 + c];
    __syncthreads();
    float acc = b1[c];
    for (int k = 0; k < 256; ++k) acc += cat[k] * W1[k * 128 + c];
    float z = fmaxf(acc, 0.f);
    float l0 = z * W2[c * 2 + 0];
    float l1 = z * W2[c * 2 + 1];
#pragma unroll
    for (int off = 32; off; off >>= 1) {
        l0 += __shfl_xor(l0, off);
        l1 += __shfl_xor(l1, off);
    }
    if ((c & 63) == 0) {
        red[(c >> 6) * 2 + 0] = l0;
        red[(c >> 6) * 2 + 1] = l1;
    }
    __syncthreads();
    if (c == 0) {
        float L0 = red[0] + red[2] + b2[0];
        float L1 = red[1] + red[3] + b2[1];
        float m = fmaxf(L0, L1);
        float lse = m + logf(expf(L0 - m) + expf(L1 - m));
        out[i * 2 + 0] = L0 - lse;
        out[i * 2 + 1] = L1 - lse;
    }
}

// ============================= contrastive loss =============================
__global__ __launch_bounds__(256) void contrast_kernel(const float* __restrict__ n_sc,
                                                       const float* __restrict__ n_fc,
                                                       float* __restrict__ loss_acc) {
    __shared__ float arow[128];
    __shared__ float redm[4];
    __shared__ float reds[4];
    __shared__ float diag_s;
    int b = blockIdx.x;
    int i = b & 255;
    bool which = b >= 256;
    const float* A  = which ? n_fc : n_sc;
    const float* B1 = which ? n_sc : n_fc;
    const float* B2 = which ? n_fc : n_sc;
    int j = threadIdx.x;
    if (j < 128) arow[j] = A[i * 128 + j];
    __syncthreads();
    float d1 = 0.f, d2 = 0.f;
    for (int k = 0; k < 128; ++k) {
        float a = arow[k];
        d1 += a * B1[(size_t)j * 128 + k];
        d2 += a * B2[(size_t)j * 128 + k];
    }
    const float t = 2.0f;  // 1/TEMPERATURE
    float v1 = t * d1;
    float v2 = (j == i) ? 0.0f : 0.8f * t * d2;
    if (j == i) diag_s = v1;
    float m = fmaxf(v1, v2);
#pragma unroll
    for (int off = 32; off; off >>= 1) m = fmaxf(m, __shfl_xor(m, off));
    if ((j & 63) == 0) redm[j >> 6] = m;
    __syncthreads();
    m = fmaxf(fmaxf(redm[0], redm[1]), fmaxf(redm[2], redm[3]));
    float s = expf(v1 - m) + expf(v2 - m);
#pragma unroll
    for (int off = 32; off; off >>= 1) s += __shfl_xor(s, off);
    if ((j & 63) == 0) reds[j >> 6] = s;
    __syncthreads();
    if (j == 0) {
        float S = reds[0] + reds[1] + reds[2] + reds[3];
        float lse = m + logf(S);
        atomicAdd(loss_acc, lse - diag_s);
    }
}

__global__ void final_add(float* __restrict__ out, const float* __restrict__ loss) {
    int t = threadIdx.x;
    if (t < 512) out[t] += loss[0] * (1.0f / 512.0f);
}

// ============================= launch =============================

extern "C" void kernel_launch(void* const* d_in, const int* in_sizes, int n_in,
                              void* d_out, int out_size, void* d_ws, size_t ws_size,
                              hipStream_t stream) {
    const float* sc_x  = (const float*)d_in[0];
    const float* fc_x  = (const float*)d_in[1];
    const int*   sc_ei = (const int*)d_in[2];
    const int*   fc_ei = (const int*)d_in[3];
    const int*   batch = (const int*)d_in[4];
    const float* sc_W  = (const float*)d_in[5];
    const float* sc_b  = (const float*)d_in[6];
    const float* fc_W  = (const float*)d_in[7];
    const float* fc_b  = (const float*)d_in[8];
    const float* fc1_W = (const float*)d_in[9];
    const float* fc1_b = (const float*)d_in[10];
    const float* fc2_W = (const float*)d_in[11];
    const float* fc2_b = (const float*)d_in[12];
    float* out = (float*)d_out;

    const size_t NF = (size_t)N_NODES * HID;  // 12.8M elements

    float* ws = (float*)d_ws;
    float* dis_sc = ws;                // N f32 (gemm epilogue float4 reads padded by dis_fc)
    float* dis_fc = dis_sc + N_NODES;  // N f32 (padded by g arrays after)
    float* g_sc  = dis_fc + N_NODES;   // g_sc,g_fc contiguous for one memset
    float* g_fc  = g_sc + NGRAPH * HID;
    float* n_sc  = g_fc + NGRAPH * HID;
    float* n_fc  = n_sc + NGRAPH * HID;
    float* lossp = n_fc + NGRAPH * HID;  // 1 (+pad)
    u16* h_sc    = (u16*)(lossp + 4);    // NF bf16 (h' = h*dis)
    u16* h_fc    = h_sc + NF;
    u16* x_sc    = h_fc + NF;            // NF bf16 activations
    u16* x_fc    = x_sc + NF;
    u16* Wtb     = x_fc + NF;            // 6*16384 bf16 (transposed weights)
    int* srcs_sc   = (int*)(Wtb + 6 * 16384);  // E
    int* srcs_fc   = srcs_sc + N_EDGES;
    int* counts_sc = srcs_fc + N_EDGES;  // N (contiguous pair for memset)
    int* counts_fc = counts_sc + N_NODES;
    int* off_sc    = counts_fc + N_NODES;  // N+1
    int* off_fc    = off_sc + (N_NODES + 1);
    int* cur_sc    = off_fc + (N_NODES + 1);  // N
    int* cur_fc    = cur_sc + N_NODES;
    int* bsum      = cur_fc + N_NODES;        // 2*NCHUNK
    (void)ws_size; (void)n_in; (void)in_sizes; (void)out_size;

    // ---- CSR build (direct per-node-cursor scatter, both branches per dispatch) ----
    hipMemsetAsync(counts_sc, 0, 2 * N_NODES * sizeof(int), stream);
    count2_kernel<<<2 * EB, 256, 0, stream>>>(sc_ei, fc_ei, counts_sc, counts_fc);
    dis2_kernel<<<2 * NB, 256, 0, stream>>>(counts_sc, counts_fc, dis_sc, dis_fc);
    block_sum_kernel<<<2 * NCHUNK, 256, 0, stream>>>(counts_sc, counts_fc, bsum);
    scan_tops_kernel<<<1, 256, 0, stream>>>(bsum);
    scan_final_kernel<<<2 * NCHUNK, 256, 0, stream>>>(counts_sc, counts_fc, bsum,
                                                      off_sc, off_fc, cur_sc, cur_fc);
    build2_kernel<<<2 * EB, 256, 0, stream>>>(sc_ei, fc_ei, cur_sc, cur_fc, srcs_sc, srcs_fc);
    convert_w_kernel<<<(6 * 16384 + 255) / 256, 256, 0, stream>>>(sc_W, fc_W, Wtb);

    // ---- 3 GCN layers, both branches per launch ----
    for (int l = 0; l < 3; ++l) {
        const void* a_sc = (l == 0) ? (const void*)sc_x : (const void*)x_sc;
        const void* a_fc = (l == 0) ? (const void*)fc_x : (const void*)x_fc;
        gemm2_kernel<<<2 * GB, 256, 0, stream>>>(a_sc, a_fc, (l == 0) ? 1 : 0, Wtb, l,
                                                 dis_sc, dis_fc, h_sc, h_fc);
        gather2_kernel<<<2 * GAT_NB, 256, 0, stream>>>(
            h_sc, h_fc, srcs_sc, srcs_fc, off_sc, off_fc,
            dis_sc, dis_fc, sc_b + (size_t)l * HID, fc_b + (size_t)l * HID, x_sc, x_fc);
    }

    // ---- pooling ----
    hipMemsetAsync(g_sc, 0, 2 * NGRAPH * HID * sizeof(float), stream);
    pool2_kernel<<<2 * PB, 128, 0, stream>>>(x_sc, x_fc, batch, g_sc, g_fc);

    // ---- head + contrastive ----
    normalize_kernel<<<512, 64, 0, stream>>>(g_sc, g_fc, n_sc, n_fc);
    head_kernel<<<NGRAPH, 128, 0, stream>>>(g_sc, g_fc, fc1_W, fc1_b, fc2_W, fc2_b, out);
    hipMemsetAsync(lossp, 0, sizeof(float), stream);
    contrast_kernel<<<512, 256, 0, stream>>>(n_sc, n_fc, lossp);
    final_add<<<1, 512, 0, stream>>>(out, lossp);
}

// Round 11
// 986.393 us; speedup vs baseline: 2.5506x; 1.1530x over previous
//
#include <hip/hip_runtime.h>
#include <math.h>

#define N_NODES 100000
#define N_EDGES 1600000
#define HID     128
#define NGRAPH  256
#define SCHUNK  1024
#define NCHUNK  ((N_NODES + SCHUNK - 1) / SCHUNK)   // 98
#define GB      ((N_NODES + 63) / 64)               // 1563 gemm blocks per branch
#define GAT_NB  (N_NODES / 4)                       // 25000 gather blocks per branch
#define EB      ((N_EDGES + 255) / 256)             // 6250
#define NB      ((N_NODES + 255) / 256)             // 391
#define PB      ((N_NODES + 63) / 64)               // 1563 pool blocks per branch
#define NBUCK   ((N_NODES + 511) / 512)             // 196 buckets (512 nodes each)
#define AVPT    16
#define ABLK    ((N_EDGES + 256 * AVPT - 1) / (256 * AVPT))  // 391 buildA blocks per branch

typedef unsigned short u16;
typedef unsigned int   u32;
typedef __attribute__((ext_vector_type(8))) short    bf16x8;
typedef __attribute__((ext_vector_type(4))) float    f32x4;
typedef __attribute__((ext_vector_type(8))) unsigned short u16x8;

__device__ inline float b2f(u16 u) {
    union { unsigned int i; float f; } x; x.i = ((unsigned int)u) << 16; return x.f;
}
__device__ inline u16 f2b(float f) {
    union { float f; unsigned int i; } x; x.f = f;
    unsigned int r = x.i + 0x7fff + ((x.i >> 16) & 1);   // round-to-nearest-even
    return (u16)(r >> 16);
}

// ============================= setup kernels =============================

__global__ void count2_kernel(const int* __restrict__ sc_ei, const int* __restrict__ fc_ei,
                              int* __restrict__ c_sc, int* __restrict__ c_fc) {
    int b = blockIdx.x;
    const int* ei = (b >= EB) ? fc_ei : sc_ei;
    int* counts   = (b >= EB) ? c_fc  : c_sc;
    int e = (b >= EB ? b - EB : b) * 256 + threadIdx.x;
    if (e < N_EDGES) atomicAdd(&counts[ei[N_EDGES + e]], 1);
}

__global__ void dis2_kernel(const int* __restrict__ c_sc, const int* __restrict__ c_fc,
                            float* __restrict__ d_sc, float* __restrict__ d_fc) {
    int b = blockIdx.x;
    const int* counts = (b >= NB) ? c_fc : c_sc;
    float* dis        = (b >= NB) ? d_fc : d_sc;
    int i = (b >= NB ? b - NB : b) * 256 + threadIdx.x;
    if (i < N_NODES) dis[i] = rsqrtf((float)counts[i] + 1.0f);
}

// ---- 3-phase multi-block exclusive scan (both branches in one grid) ----
__global__ __launch_bounds__(256) void block_sum_kernel(const int* __restrict__ c_sc,
                                                        const int* __restrict__ c_fc,
                                                        int* __restrict__ bsum) {
    int branch = blockIdx.x / NCHUNK;
    int chunk  = blockIdx.x % NCHUNK;
    const int* counts = branch ? c_fc : c_sc;
    int base = chunk * SCHUNK;
    int tid = threadIdx.x;
    int v = 0;
    for (int i = tid; i < SCHUNK; i += 256) {
        int idx = base + i;
        if (idx < N_NODES) v += counts[idx];
    }
    __shared__ int red[4];
#pragma unroll
    for (int off = 32; off; off >>= 1) v += __shfl_down(v, off);
    if ((tid & 63) == 0) red[tid >> 6] = v;
    __syncthreads();
    if (tid == 0) bsum[blockIdx.x] = red[0] + red[1] + red[2] + red[3];
}

__global__ __launch_bounds__(256) void scan_tops_kernel(int* __restrict__ bsum) {
    __shared__ int lds[2][128];
    int tid = threadIdx.x;
    int branch = tid >> 7;
    int i = tid & 127;
    int orig = (i < NCHUNK) ? bsum[branch * NCHUNK + i] : 0;
    lds[branch][i] = orig;
    __syncthreads();
    for (int off = 1; off < 128; off <<= 1) {
        int t = (i >= off) ? lds[branch][i - off] : 0;
        __syncthreads();
        lds[branch][i] += t;
        __syncthreads();
    }
    if (i < NCHUNK) bsum[branch * NCHUNK + i] = lds[branch][i] - orig;  // exclusive
}

__global__ __launch_bounds__(256) void scan_final_kernel(
        const int* __restrict__ c_sc, const int* __restrict__ c_fc,
        const int* __restrict__ bsum,
        int* __restrict__ off_sc, int* __restrict__ off_fc) {
    int branch = blockIdx.x / NCHUNK;
    int chunk  = blockIdx.x % NCHUNK;
    const int* counts = branch ? c_fc : c_sc;
    int* offs = branch ? off_fc : off_sc;
    int tid = threadIdx.x;
    int base = chunk * SCHUNK + tid * 4;
    int v[4], s = 0;
#pragma unroll
    for (int k = 0; k < 4; ++k) {
        int idx = base + k;
        v[k] = (idx < N_NODES) ? counts[idx] : 0;
        s += v[k];
    }
    __shared__ int lds[256];
    lds[tid] = s;
    __syncthreads();
    for (int off = 1; off < 256; off <<= 1) {
        int t = (tid >= off) ? lds[tid - off] : 0;
        __syncthreads();
        lds[tid] += t;
        __syncthreads();
    }
    int prefix = bsum[blockIdx.x] + lds[tid] - s;
#pragma unroll
    for (int k = 0; k < 4; ++k) {
        int idx = base + k;
        if (idx < N_NODES) offs[idx] = prefix;
        prefix += v[k];
    }
    if (blockIdx.x == 0 && tid == 0) { off_sc[N_NODES] = N_EDGES; off_fc[N_NODES] = N_EDGES; }
}

// ---- bucket cursor init: bcur[branch][k] = off[k*512] ----
__global__ void bcur_init_kernel(const int* __restrict__ off_sc, const int* __restrict__ off_fc,
                                 int* __restrict__ bcur) {
    int t = threadIdx.x;  // one block of 512 covers 2*NBUCK=392
    if (t >= 2 * NBUCK) return;
    int branch = t >= NBUCK;
    int k = branch ? t - NBUCK : t;
    const int* off = branch ? off_fc : off_sc;
    bcur[t] = off[k << 9];
}

// ---- pass A (two-sweep): LDS histogram sweep -> one global reservation per
// (block,bucket) -> scatter sweep. Writes land in per-block bucket ranges
// (~21 recs = 1-2 cache lines), killing the 12x write amplification of the
// direct per-node scatter. 391 atomic adds per bucket counter (vs 8163
// per-node-cursor adds of the round-4 pathology).
__global__ __launch_bounds__(256) void buildA_kernel(
        const int* __restrict__ sc_ei, const int* __restrict__ fc_ei,
        int* __restrict__ bcur,
        u32* __restrict__ tmp_sc, u32* __restrict__ tmp_fc) {
    int b = blockIdx.x;
    int branch = b >= ABLK;
    int blk = branch ? b - ABLK : b;
    const int* ei = branch ? fc_ei : sc_ei;
    u32* tmp      = branch ? tmp_fc : tmp_sc;
    int* bc       = bcur + (branch ? NBUCK : 0);

    __shared__ int hist[NBUCK];
    __shared__ int cur[NBUCK];
    int tid = threadIdx.x;
    for (int i = tid; i < NBUCK; i += 256) hist[i] = 0;
    __syncthreads();

    int e0 = blk * (256 * AVPT) + tid;
    // sweep 1: histogram of destination buckets
    for (int k = 0; k < AVPT; ++k) {
        int e = e0 + k * 256;
        if (e < N_EDGES) atomicAdd(&hist[ei[N_EDGES + e] >> 9], 1);
    }
    __syncthreads();
    // reserve a contiguous global range per bucket for this block
    for (int i = tid; i < NBUCK; i += 256) {
        int c = hist[i];
        cur[i] = c ? atomicAdd(&bc[i], c) : 0;
    }
    __syncthreads();
    // sweep 2: scatter packed records into reserved ranges
    for (int k = 0; k < AVPT; ++k) {
        int e = e0 + k * 256;
        if (e < N_EDGES) {
            int s = ei[e], d = ei[N_EDGES + e];
            int pos = atomicAdd(&cur[d >> 9], 1);   // LDS cursor holds global slot
            tmp[pos] = ((u32)s << 9) | (u32)(d & 511);
        }
    }
}

// ---- pass B: per-bucket LDS-cursor scatter into final CSR srcs (2KB windows) ----
__global__ __launch_bounds__(256) void buildB_kernel(
        const u32* __restrict__ tmp_sc, const u32* __restrict__ tmp_fc,
        const int* __restrict__ off_sc, const int* __restrict__ off_fc,
        int* __restrict__ srcs_sc, int* __restrict__ srcs_fc) {
    int b = blockIdx.x;
    int branch = b >= NBUCK;
    int bucket = branch ? b - NBUCK : b;
    const u32* tmp = branch ? tmp_fc : tmp_sc;
    const int* off = branch ? off_fc : off_sc;
    int* srcs      = branch ? srcs_fc : srcs_sc;
    int node0 = bucket << 9;
    int nEnd = min(node0 + 512, N_NODES);
    __shared__ int cur[512];
    int tid = threadIdx.x;
    for (int i = tid; i < 512; i += 256)
        cur[i] = (node0 + i <= N_NODES) ? off[node0 + i] : N_EDGES;
    __syncthreads();
    int beg = off[node0];
    int end = off[nEnd];
    for (int r = beg + tid; r < end; r += 256) {
        u32 rec = tmp[r];
        int local = rec & 511;
        int src = rec >> 9;
        int pos = atomicAdd(&cur[local], 1);
        srcs[pos] = src;
    }
}

// ---- pre-convert+transpose weights: Wt[l'][n][k] = W[l][k][n] (bf16), l' = branch*3+l ----
__global__ void convert_w_kernel(const float* __restrict__ sc_W, const float* __restrict__ fc_W,
                                 u16* __restrict__ Wt) {
    int idx = blockIdx.x * 256 + threadIdx.x;  // 6*16384 total
    if (idx >= 6 * 16384) return;
    int lp = idx >> 14;
    int r = idx & 16383;
    int n = r >> 7, k = r & 127;
    const float* W = (lp >= 3) ? fc_W : sc_W;
    int l = (lp >= 3) ? lp - 3 : lp;
    Wt[idx] = f2b(W[(size_t)l * 16384 + k * 128 + n]);
}

// ============================= MFMA GEMM: H'[n] = (bf16(A[n]) @ W) * dis[n] =============================
__global__ __launch_bounds__(256) void gemm2_kernel(
        const void* __restrict__ A_sc, const void* __restrict__ A_fc, int a_fp32,
        const u16* __restrict__ Wt, int layer,
        const float* __restrict__ d_sc, const float* __restrict__ d_fc,
        u16* __restrict__ H_sc, u16* __restrict__ H_fc) {
    int branch = blockIdx.x >= GB;
    int blk = branch ? blockIdx.x - GB : blockIdx.x;
    const void* A = branch ? A_fc : A_sc;
    const float* dis = branch ? d_fc : d_sc;
    u16* H = branch ? H_fc : H_sc;
    const u16* W = Wt + (((size_t)branch * 3 + layer) << 14);

    __shared__ u16 Alds[64 * 136];   // rows padded to 136 u16 (272 B)
    __shared__ u16 Wlds[128 * 136];  // Wt rows: n-major, k contiguous
    const int tid = threadIdx.x;
    const int row0 = blk * 64;

    if (a_fp32) {
        const float* Af = (const float*)A;
#pragma unroll
        for (int i = 0; i < 8; ++i) {
            int idx = tid + i * 256;
            int r = idx >> 5, f = idx & 31;
            int grow = row0 + r;
            float4 v = (grow < N_NODES) ? *(const float4*)&Af[(size_t)grow * 128 + f * 4]
                                        : make_float4(0.f, 0.f, 0.f, 0.f);
            ushort4 o;
            o.x = f2b(v.x); o.y = f2b(v.y); o.z = f2b(v.z); o.w = f2b(v.w);
            *(ushort4*)&Alds[r * 136 + f * 4] = o;
        }
    } else {
        const u16* Ab = (const u16*)A;
#pragma unroll
        for (int i = 0; i < 4; ++i) {
            int idx = tid + i * 256;
            int r = idx >> 4, f = idx & 15;
            int grow = row0 + r;
            u16x8 v = {};
            if (grow < N_NODES) v = *(const u16x8*)&Ab[(size_t)grow * 128 + f * 8];
            *(u16x8*)&Alds[r * 136 + f * 8] = v;
        }
    }
#pragma unroll
    for (int i = 0; i < 8; ++i) {
        int idx = tid + i * 256;
        int n = idx >> 4, f = idx & 15;
        *(u16x8*)&Wlds[n * 136 + f * 8] = *(const u16x8*)&W[n * 128 + f * 8];
    }
    __syncthreads();

    const int wv = tid >> 6;
    const int lane = tid & 63;
    const int m = lane & 15;       // row (A) / col (B) within 16-tile
    const int quad = lane >> 4;    // k-subchunk

    bf16x8 af[4];
#pragma unroll
    for (int kt = 0; kt < 4; ++kt)
        af[kt] = *(const bf16x8*)&Alds[(wv * 16 + m) * 136 + kt * 32 + quad * 8];

    f32x4 acc[8];
#pragma unroll
    for (int ct = 0; ct < 8; ++ct) { acc[ct][0] = 0.f; acc[ct][1] = 0.f; acc[ct][2] = 0.f; acc[ct][3] = 0.f; }

#pragma unroll
    for (int ct = 0; ct < 8; ++ct) {
#pragma unroll
        for (int kt = 0; kt < 4; ++kt) {
            bf16x8 bf = *(const bf16x8*)&Wlds[(ct * 16 + m) * 136 + kt * 32 + quad * 8];
            acc[ct] = __builtin_amdgcn_mfma_f32_16x16x32_bf16(af[kt], bf, acc[ct], 0, 0, 0);
        }
    }

    // fold dis: rows quad*4..quad*4+3 of this wave's 16-row tile (contiguous -> float4)
    float4 dv = *(const float4*)&dis[row0 + wv * 16 + quad * 4];  // ws-padded, OOB-safe
#pragma unroll
    for (int ct = 0; ct < 8; ++ct) {
        acc[ct][0] *= dv.x; acc[ct][1] *= dv.y; acc[ct][2] *= dv.z; acc[ct][3] *= dv.w;
    }

    // epilogue: C/D layout col=lane&15, row=quad*4+reg -> LDS -> coalesced bf16 stores
#pragma unroll
    for (int ct = 0; ct < 8; ++ct)
#pragma unroll
        for (int r = 0; r < 4; ++r)
            Alds[(wv * 16 + quad * 4 + r) * 136 + ct * 16 + m] = f2b(acc[ct][r]);
    __syncthreads();
#pragma unroll
    for (int i = 0; i < 4; ++i) {
        int idx = i * 64 + lane;
        int r = idx >> 4, f = idx & 15;
        int grow = row0 + wv * 16 + r;
        if (grow < N_NODES)
            *(u16x8*)&H[(size_t)grow * 128 + f * 8] = *(const u16x8*)&Alds[(wv * 16 + r) * 136 + f * 8];
    }
}

// ============================= GCN aggregation: x[n] = relu(dis[n]*(sum h'[src] + h'[n]) + b) =============================
// Wave per node; quarter-wave (16 lanes x u16x8 = full 256B row) per edge, 2-way unroll.
__global__ __launch_bounds__(256) void gather2_kernel(
        const u16* __restrict__ h_sc, const u16* __restrict__ h_fc,
        const int* __restrict__ srcs_sc, const int* __restrict__ srcs_fc,
        const int* __restrict__ off_sc, const int* __restrict__ off_fc,
        const float* __restrict__ d_sc, const float* __restrict__ d_fc,
        const float* __restrict__ b_sc, const float* __restrict__ b_fc,
        u16* __restrict__ x_sc, u16* __restrict__ x_fc) {
    int bb = blockIdx.x;
    int branch = bb >= GAT_NB;
    if (branch) bb -= GAT_NB;
    const u16* h    = branch ? h_fc : h_sc;
    const int* srcs = branch ? srcs_fc : srcs_sc;
    const int* offs = branch ? off_fc : off_sc;
    const float* dis = branch ? d_fc : d_sc;
    const float* bias = branch ? b_fc : b_sc;
    u16* xout = branch ? x_fc : x_sc;

    int node = bb * 4 + (threadIdx.x >> 6);
    int lane = threadIdx.x & 63;
    int quarter = lane >> 4;        // 0..3: which edge of each group of 4 this quarter owns
    int c = (lane & 15) * 8;        // feature chunk of 8 bf16 (16B)
    int beg = offs[node], end = offs[node + 1];
    float acc[8] = {0.f, 0.f, 0.f, 0.f, 0.f, 0.f, 0.f, 0.f};
    int j = beg + quarter;
    for (; j + 4 < end; j += 8) {
        int s0 = srcs[j], s1 = srcs[j + 4];
        u16x8 v0 = *(const u16x8*)&h[(size_t)s0 * 128 + c];
        u16x8 v1 = *(const u16x8*)&h[(size_t)s1 * 128 + c];
#pragma unroll
        for (int t = 0; t < 8; ++t) acc[t] += b2f(v0[t]) + b2f(v1[t]);
    }
    if (j < end) {
        int s0 = srcs[j];
        u16x8 v0 = *(const u16x8*)&h[(size_t)s0 * 128 + c];
#pragma unroll
        for (int t = 0; t < 8; ++t) acc[t] += b2f(v0[t]);
    }
#pragma unroll
    for (int t = 0; t < 8; ++t) {
        acc[t] += __shfl_xor(acc[t], 16);
        acc[t] += __shfl_xor(acc[t], 32);
    }
    if (quarter == 0) {
        float dn = dis[node];
        u16x8 hv = *(const u16x8*)&h[(size_t)node * 128 + c];  // h' self row
        float4 b0 = *(const float4*)&bias[c];
        float4 b1 = *(const float4*)&bias[c + 4];
        float bv[8] = {b0.x, b0.y, b0.z, b0.w, b1.x, b1.y, b1.z, b1.w};
        u16x8 o;
#pragma unroll
        for (int t = 0; t < 8; ++t)
            o[t] = f2b(fmaxf(dn * (acc[t] + b2f(hv[t])) + bv[t], 0.f));
        *(u16x8*)&xout[(size_t)node * 128 + c] = o;
    }
}

// ============================= pooling (batch is sorted; x is bf16, fp32 accumulate) =============================
__global__ __launch_bounds__(128) void pool2_kernel(const u16* __restrict__ x_sc,
                                                    const u16* __restrict__ x_fc,
                                                    const int* __restrict__ batch,
                                                    float* __restrict__ g_sc,
                                                    float* __restrict__ g_fc) {
    int b = blockIdx.x;
    const u16* x = (b >= PB) ? x_fc : x_sc;
    float* g     = (b >= PB) ? g_fc : g_sc;
    int blk = (b >= PB) ? b - PB : b;
    int c = threadIdx.x;
    int start = blk * 64;
    if (start >= N_NODES) return;
    int endn = min(start + 64, N_NODES);
    float acc = 0.f;
    int cur = batch[start];
    for (int i = start; i < endn; ++i) {
        int bb = batch[i];
        if (bb != cur) {
            atomicAdd(&g[(size_t)cur * 128 + c], acc);
            acc = 0.f;
            cur = bb;
        }
        acc += b2f(x[(size_t)i * 128 + c]);
    }
    atomicAdd(&g[(size_t)cur * 128 + c], acc);
}

// ============================= row L2-normalize =============================
__global__ __launch_bounds__(64) void normalize_kernel(const float* __restrict__ g_sc,
                                                       const float* __restrict__ g_fc,
                                                       float* __restrict__ n_sc,
                                                       float* __restrict__ n_fc) {
    int r = blockIdx.x & 255;
    const float* g = (blockIdx.x < 256) ? g_sc : g_fc;
    float* o = (blockIdx.x < 256) ? n_sc : n_fc;
    int c = threadIdx.x;
    float v0 = g[r * 128 + c], v1 = g[r * 128 + c + 64];
    float ss = v0 * v0 + v1 * v1;
#pragma unroll
    for (int off = 32; off; off >>= 1) ss += __shfl_xor(ss, off);
    float inv = 1.0f / fmaxf(sqrtf(ss), 1e-12f);
    o[r * 128 + c] = v0 * inv;
    o[r * 128 + c + 64] = v1 * inv;
}

// ============================= classifier head =============================
__global__ __launch_bounds__(128) void head_kernel(const float* __restrict__ g_sc,
                                                   const float* __restrict__ g_fc,
                                                   const float* __restrict__ W1,
                                                   const float* __restrict__ b1,
                                                   const float* __restrict__ W2,
                                                   const float* __restrict__ b2,
                                                   float* __restrict__ out) {
    __shared__ float cat[256];
    __shared__ float red[4];
    int i = blockIdx.x, c = threadIdx.x;
    cat[c] = g_sc[i * 128 + c];
    cat[128 + c] = g_fc[i * 128 + c];
    __syncthreads();
    float acc = b1[c];
    for (int k = 0; k < 256; ++k) acc += cat[k] * W1[k * 128 + c];
    float z = fmaxf(acc, 0.f);
    float l0 = z * W2[c * 2 + 0];
    float l1 = z * W2[c * 2 + 1];
#pragma unroll
    for (int off = 32; off; off >>= 1) {
        l0 += __shfl_xor(l0, off);
        l1 += __shfl_xor(l1, off);
    }
    if ((c & 63) == 0) {
        red[(c >> 6) * 2 + 0] = l0;
        red[(c >> 6) * 2 + 1] = l1;
    }
    __syncthreads();
    if (c == 0) {
        float L0 = red[0] + red[2] + b2[0];
        float L1 = red[1] + red[3] + b2[1];
        float m = fmaxf(L0, L1);
        float lse = m + logf(expf(L0 - m) + expf(L1 - m));
        out[i * 2 + 0] = L0 - lse;
        out[i * 2 + 1] = L1 - lse;
    }
}

// ============================= contrastive loss =============================
__global__ __launch_bounds__(256) void contrast_kernel(const float* __restrict__ n_sc,
                                                       const float* __restrict__ n_fc,
                                                       float* __restrict__ loss_acc) {
    __shared__ float arow[128];
    __shared__ float redm[4];
    __shared__ float reds[4];
    __shared__ float diag_s;
    int b = blockIdx.x;
    int i = b & 255;
    bool which = b >= 256;
    const float* A  = which ? n_fc : n_sc;
    const float* B1 = which ? n_sc : n_fc;
    const float* B2 = which ? n_fc : n_sc;
    int j = threadIdx.x;
    if (j < 128) arow[j] = A[i * 128 + j];
    __syncthreads();
    float d1 = 0.f, d2 = 0.f;
    for (int k = 0; k < 128; ++k) {
        float a = arow[k];
        d1 += a * B1[(size_t)j * 128 + k];
        d2 += a * B2[(size_t)j * 128 + k];
    }
    const float t = 2.0f;  // 1/TEMPERATURE
    float v1 = t * d1;
    float v2 = (j == i) ? 0.0f : 0.8f * t * d2;
    if (j == i) diag_s = v1;
    float m = fmaxf(v1, v2);
#pragma unroll
    for (int off = 32; off; off >>= 1) m = fmaxf(m, __shfl_xor(m, off));
    if ((j & 63) == 0) redm[j >> 6] = m;
    __syncthreads();
    m = fmaxf(fmaxf(redm[0], redm[1]), fmaxf(redm[2], redm[3]));
    float s = expf(v1 - m) + expf(v2 - m);
#pragma unroll
    for (int off = 32; off; off >>= 1) s += __shfl_xor(s, off);
    if ((j & 63) == 0) reds[j >> 6] = s;
    __syncthreads();
    if (j == 0) {
        float S = reds[0] + reds[1] + reds[2] + reds[3];
        float lse = m + logf(S);
        atomicAdd(loss_acc, lse - diag_s);
    }
}

__global__ void final_add(float* __restrict__ out, const float* __restrict__ loss) {
    int t = threadIdx.x;
    if (t < 512) out[t] += loss[0] * (1.0f / 512.0f);
}

// ============================= launch =============================

extern "C" void kernel_launch(void* const* d_in, const int* in_sizes, int n_in,
                              void* d_out, int out_size, void* d_ws, size_t ws_size,
                              hipStream_t stream) {
    const float* sc_x  = (const float*)d_in[0];
    const float* fc_x  = (const float*)d_in[1];
    const int*   sc_ei = (const int*)d_in[2];
    const int*   fc_ei = (const int*)d_in[3];
    const int*   batch = (const int*)d_in[4];
    const float* sc_W  = (const float*)d_in[5];
    const float* sc_b  = (const float*)d_in[6];
    const float* fc_W  = (const float*)d_in[7];
    const float* fc_b  = (const float*)d_in[8];
    const float* fc1_W = (const float*)d_in[9];
    const float* fc1_b = (const float*)d_in[10];
    const float* fc2_W = (const float*)d_in[11];
    const float* fc2_b = (const float*)d_in[12];
    float* out = (float*)d_out;

    const size_t NF = (size_t)N_NODES * HID;  // 12.8M elements

    float* ws = (float*)d_ws;
    float* dis_sc = ws;                // N f32 (gemm epilogue float4 reads padded by dis_fc)
    float* dis_fc = dis_sc + N_NODES;  // N f32 (padded by g arrays after)
    float* g_sc  = dis_fc + N_NODES;   // g_sc,g_fc contiguous for one memset
    float* g_fc  = g_sc + NGRAPH * HID;
    float* n_sc  = g_fc + NGRAPH * HID;
    float* n_fc  = n_sc + NGRAPH * HID;
    float* lossp = n_fc + NGRAPH * HID;  // 1 (+pad)
    u16* h_sc    = (u16*)(lossp + 4);    // NF bf16 (h' = h*dis)
    u16* h_fc    = h_sc + NF;
    u16* x_sc    = h_fc + NF;            // NF bf16 activations
    u16* x_fc    = x_sc + NF;
    u16* Wtb     = x_fc + NF;            // 6*16384 bf16 (transposed weights)
    int* srcs_sc   = (int*)(Wtb + 6 * 16384);  // E
    int* srcs_fc   = srcs_sc + N_EDGES;
    u32* tmp_sc    = (u32*)(srcs_fc + N_EDGES);  // E packed records
    u32* tmp_fc    = tmp_sc + N_EDGES;
    int* counts_sc = (int*)(tmp_fc + N_EDGES);   // N (contiguous pair for memset)
    int* counts_fc = counts_sc + N_NODES;
    int* off_sc    = counts_fc + N_NODES;  // N+1
    int* off_fc    = off_sc + (N_NODES + 1);
    int* bcur      = off_fc + (N_NODES + 1);  // 2*NBUCK
    int* bsum      = bcur + 2 * NBUCK;        // 2*NCHUNK
    (void)ws_size; (void)n_in; (void)in_sizes; (void)out_size;

    // ---- CSR build (bucketed two-pass with block-range reservation) ----
    hipMemsetAsync(counts_sc, 0, 2 * N_NODES * sizeof(int), stream);
    count2_kernel<<<2 * EB, 256, 0, stream>>>(sc_ei, fc_ei, counts_sc, counts_fc);
    dis2_kernel<<<2 * NB, 256, 0, stream>>>(counts_sc, counts_fc, dis_sc, dis_fc);
    block_sum_kernel<<<2 * NCHUNK, 256, 0, stream>>>(counts_sc, counts_fc, bsum);
    scan_tops_kernel<<<1, 256, 0, stream>>>(bsum);
    scan_final_kernel<<<2 * NCHUNK, 256, 0, stream>>>(counts_sc, counts_fc, bsum, off_sc, off_fc);
    bcur_init_kernel<<<1, 512, 0, stream>>>(off_sc, off_fc, bcur);
    buildA_kernel<<<2 * ABLK, 256, 0, stream>>>(sc_ei, fc_ei, bcur, tmp_sc, tmp_fc);
    buildB_kernel<<<2 * NBUCK, 256, 0, stream>>>(tmp_sc, tmp_fc, off_sc, off_fc, srcs_sc, srcs_fc);
    convert_w_kernel<<<(6 * 16384 + 255) / 256, 256, 0, stream>>>(sc_W, fc_W, Wtb);

    // ---- 3 GCN layers, both branches per launch ----
    for (int l = 0; l < 3; ++l) {
        const void* a_sc = (l == 0) ? (const void*)sc_x : (const void*)x_sc;
        const void* a_fc = (l == 0) ? (const void*)fc_x : (const void*)x_fc;
        gemm2_kernel<<<2 * GB, 256, 0, stream>>>(a_sc, a_fc, (l == 0) ? 1 : 0, Wtb, l,
                                                 dis_sc, dis_fc, h_sc, h_fc);
        gather2_kernel<<<2 * GAT_NB, 256, 0, stream>>>(
            h_sc, h_fc, srcs_sc, srcs_fc, off_sc, off_fc,
            dis_sc, dis_fc, sc_b + (size_t)l * HID, fc_b + (size_t)l * HID, x_sc, x_fc);
    }

    // ---- pooling ----
    hipMemsetAsync(g_sc, 0, 2 * NGRAPH * HID * sizeof(float), stream);
    pool2_kernel<<<2 * PB, 128, 0, stream>>>(x_sc, x_fc, batch, g_sc, g_fc);

    // ---- head + contrastive ----
    normalize_kernel<<<512, 64, 0, stream>>>(g_sc, g_fc, n_sc, n_fc);
    head_kernel<<<NGRAPH, 128, 0, stream>>>(g_sc, g_fc, fc1_W, fc1_b, fc2_W, fc2_b, out);
    hipMemsetAsync(lossp, 0, sizeof(float), stream);
    contrast_kernel<<<512, 256, 0, stream>>>(n_sc, n_fc, lossp);
    final_add<<<1, 512, 0, stream>>>(out, lossp);
}